// Round 8
// baseline (586.630 us; speedup 1.0000x reference)
//
#include <hip/hip_runtime.h>
#include <cstddef>
#include <cstdint>

// ---------------------------------------------------------------------------
// HGT forward for MI355X. C=128, H=8, D=16, OUT=64, L=2
//   NN = {30000, 60000, 6000}, NE = {200000, 300000, 200000, 100000}
//   ETS = {(0,1),(1,1),(1,2),(2,0)}
// Round-17 changes:
//  * gemm_proj_all: rb-major block ordering (cp varies fastest) -- the 5/3/3
//    blocks sharing the same A rows are now dispatch-adjacent, so A re-reads
//    hit L2/L3 before the 104 MB/layer write stream evicts them (r2 counter
//    evidence: FETCH 52 MB vs 25 MB A-size = 2x A from HBM). Panels/block
//    8->4 (grid 803->1601) smooths the 2-blocks/CU residency drain tail.
//  * agg_all: UNCHANGED -- pinned at 64-65us across 4 structural variants
//    (prefetch/sort/split/et-parallel); random-gather service equilibrium.
// ---------------------------------------------------------------------------

typedef __attribute__((ext_vector_type(8))) short short8;   // 8 x bf16
typedef __attribute__((ext_vector_type(4))) float floatx4;

__device__ __forceinline__ float gelu_fast(float x) {
    float u = 1.5957691216057308f * x * (1.0f + 0.044715f * x * x);
    return x / (1.0f + __expf(-u));
}

__device__ __forceinline__ unsigned short f2bf(float f) {   // RNE fp32->bf16
    unsigned u = __float_as_uint(f);
    u += 0x7fffu + ((u >> 16) & 1);
    return (unsigned short)(u >> 16);
}

__device__ __forceinline__ float bf2f(unsigned short h) {
    return __uint_as_float((unsigned)h << 16);
}

__device__ __forceinline__ void up8(uint4 u, float* f) {    // 8 bf16 -> 8 fp32
    f[0] = __uint_as_float(u.x << 16); f[1] = __uint_as_float(u.x & 0xffff0000u);
    f[2] = __uint_as_float(u.y << 16); f[3] = __uint_as_float(u.y & 0xffff0000u);
    f[4] = __uint_as_float(u.z << 16); f[5] = __uint_as_float(u.z & 0xffff0000u);
    f[6] = __uint_as_float(u.w << 16); f[7] = __uint_as_float(u.w & 0xffff0000u);
}

__device__ __forceinline__ uint4 pk8(const float* f) {      // 8 fp32 -> 8 bf16
    uint4 u;
    u.x = (unsigned)f2bf(f[0]) | ((unsigned)f2bf(f[1]) << 16);
    u.y = (unsigned)f2bf(f[2]) | ((unsigned)f2bf(f[3]) << 16);
    u.z = (unsigned)f2bf(f[4]) | ((unsigned)f2bf(f[5]) << 16);
    u.w = (unsigned)f2bf(f[6]) | ((unsigned)f2bf(f[7]) << 16);
    return u;
}

// ---------------- W-resident streaming MFMA GEMM (packed proj) -------------
// rb-major: cp varies fastest so same-A-rows blocks are dispatch-adjacent.
// road [0,1175) = 235 rb x 5 cp / poi [1175,1529) = 118 rb x 3 cp /
// region [1529,1601) = 24 rb x 3 cp. 4 panels (256 rows) per block.
__global__ __launch_bounds__(256, 2) void gemm_proj_all(
    const unsigned short* __restrict__ xs_bf,
    const unsigned short* __restrict__ Wl,     // Wpack + l*180224
    const float* __restrict__ bl,              // bpack + l*1408
    unsigned short* __restrict__ proj)
{
    const int    NN_[3]  = {30000, 60000, 6000};
    const int    NPAN[3] = {469, 938, 94};
    const int    OFFr[3] = {0, 30000, 90000};
    const int    WOFF[3] = {0, 49152, 131072};
    const int    BOFF[3] = {0, 384, 1024};
    const size_t POFF[3] = {0, 11520000u, 49920000u};
    const int    LDO[3]  = {384, 640, 384};

    int b = blockIdx.x, t, cp, rb;
    if (b < 1175)      { t = 1; rb = b / 5; cp = b - rb * 5; }
    else if (b < 1529) { int lb = b - 1175; t = 0; rb = lb / 3; cp = lb - rb * 3; }
    else               { int lb = b - 1529; t = 2; rb = lb / 3; cp = lb - rb * 3; }
    int p0 = rb * 4, p1 = p0 + 4;
    if (p1 > NPAN[t]) p1 = NPAN[t];
    if (p0 >= NPAN[t]) return;

    const unsigned short* Abf = xs_bf + (size_t)OFFr[t] * 128;
    const unsigned short* Wt  = Wl + WOFF[t];
    const float* bias = bl + BOFF[t] + cp * 128;
    unsigned short* outbf = proj + POFF[t];
    const int ldo = LDO[t], Nrows = NN_[t];

    const int wave = threadIdx.x >> 6, lane = threadIdx.x & 63;
    const int quad = lane >> 4, l16 = lane & 15;

    short8 B[2][4][4];
    {
        const unsigned short* wb = Wt + (size_t)(cp * 128 + l16) * 128 + quad * 8;
        #pragma unroll
        for (int T = 0; T < 2; ++T)
            #pragma unroll
            for (int c = 0; c < 4; ++c)
                #pragma unroll
                for (int kc = 0; kc < 4; ++kc)
                    B[T][c][kc] = *(const short8*)(wb + (size_t)(T * 64 + c * 16) * 128 + kc * 32);
    }
    float4 bv[2][4];
    #pragma unroll
    for (int T = 0; T < 2; ++T)
        #pragma unroll
        for (int c = 0; c < 4; ++c)
            bv[T][c] = *(const float4*)(bias + T * 64 + c * 16 + quad * 4);

    short8 Acur[4];
    {
        int m = p0 * 64 + wave * 16 + l16; if (m >= Nrows) m = Nrows - 1;
        const unsigned short* ap = Abf + (size_t)m * 128 + quad * 8;
        #pragma unroll
        for (int kc = 0; kc < 4; ++kc) Acur[kc] = *(const short8*)(ap + kc * 32);
    }
    for (int p = p0; p < p1; ++p) {
        short8 Anx[4];
        {
            int m = (p + 1) * 64 + wave * 16 + l16; if (m >= Nrows) m = Nrows - 1;
            const unsigned short* ap = Abf + (size_t)m * 128 + quad * 8;
            #pragma unroll
            for (int kc = 0; kc < 4; ++kc) Anx[kc] = *(const short8*)(ap + kc * 32);
        }
        floatx4 acc[2][4];
        #pragma unroll
        for (int T = 0; T < 2; ++T)
            #pragma unroll
            for (int c = 0; c < 4; ++c) acc[T][c] = (floatx4){0.f, 0.f, 0.f, 0.f};
        #pragma unroll
        for (int kc = 0; kc < 4; ++kc)
            #pragma unroll
            for (int T = 0; T < 2; ++T)
                #pragma unroll
                for (int c = 0; c < 4; ++c)
                    acc[T][c] = __builtin_amdgcn_mfma_f32_16x16x32_bf16(B[T][c][kc], Acur[kc], acc[T][c], 0, 0, 0);
        int node = p * 64 + wave * 16 + l16;
        if (node < Nrows) {
            unsigned short* op = outbf + (size_t)node * ldo + cp * 128 + quad * 4;
            #pragma unroll
            for (int T = 0; T < 2; ++T)
                #pragma unroll
                for (int c = 0; c < 4; ++c) {
                    uint2 u;
                    u.x = (unsigned)f2bf(acc[T][c][0] + bv[T][c].x) |
                          ((unsigned)f2bf(acc[T][c][1] + bv[T][c].y) << 16);
                    u.y = (unsigned)f2bf(acc[T][c][2] + bv[T][c].z) |
                          ((unsigned)f2bf(acc[T][c][3] + bv[T][c].w) << 16);
                    *(uint2*)(op + T * 64 + c * 16) = u;
                }
        }
        #pragma unroll
        for (int kc = 0; kc < 4; ++kc) Acur[kc] = Anx[kc];
    }
}

// ---------------- fused-by-type node GEMM (input linear / node update) -----
template<bool AF32, bool GIN, bool SKIP>
__global__ __launch_bounds__(256, 2) void gemm_node(
    const void* __restrict__ a0v, const void* __restrict__ a1v, const void* __restrict__ a2v,
    const unsigned short* __restrict__ WtB, const float* __restrict__ biasB,
    const unsigned short* __restrict__ xoldB, const float* __restrict__ skipB,
    unsigned short* __restrict__ outB)
{
    const int TN[3]   = {30000, 60000, 6000};
    const int NPAN[3] = {469, 938, 94};
    const int TOFF[3] = {0, 30000, 90000};
    int b = blockIdx.x, t, rb;
    if (b < 235)      { t = 0; rb = b; }
    else if (b < 704) { t = 1; rb = b - 235; }
    else              { t = 2; rb = b - 704; }
    int p0 = rb * 2, p1 = p0 + 2;
    if (p1 > NPAN[t]) p1 = NPAN[t];
    int Nrows = TN[t];
    const void* av = (t == 0) ? a0v : (t == 1) ? a1v : a2v;
    const unsigned short* xold = xoldB + (size_t)TOFF[t] * 128;
    unsigned short* out = outB + (size_t)TOFF[t] * 128;

    const int wave = threadIdx.x >> 6, lane = threadIdx.x & 63;
    const int quad = lane >> 4, l16 = lane & 15;

    short8 B[8][4];
    {
        const unsigned short* wb = WtB + (size_t)t * 16384 + (size_t)l16 * 128 + quad * 8;
        #pragma unroll
        for (int c = 0; c < 8; ++c)
            #pragma unroll
            for (int kc = 0; kc < 4; ++kc)
                B[c][kc] = *(const short8*)(wb + (size_t)c * 2048 + kc * 32);
    }
    float beta = 0.f, omb = 0.f;
    if (SKIP) { beta = 1.0f / (1.0f + __expf(-skipB[t])); omb = 1.0f - beta; }

    short8 Acur[4];
    {
        int m = p0 * 64 + wave * 16 + l16; if (m >= Nrows) m = Nrows - 1;
        size_t base = (size_t)m * 128 + quad * 8;
        #pragma unroll
        for (int kc = 0; kc < 4; ++kc) {
            if (AF32) {
                const float* ap = (const float*)av + base;
                float4 f0 = *(const float4*)(ap + kc * 32);
                float4 f1 = *(const float4*)(ap + kc * 32 + 4);
                float af[8] = {f0.x, f0.y, f0.z, f0.w, f1.x, f1.y, f1.z, f1.w};
                short8 a;
                #pragma unroll
                for (int i = 0; i < 8; ++i) a[i] = (short)f2bf(af[i]);
                Acur[kc] = a;
            } else if (GIN) {
                const unsigned short* ap = (const unsigned short*)av + base;
                short8 a8 = *(const short8*)(ap + kc * 32);
                short8 a;
                #pragma unroll
                for (int i = 0; i < 8; ++i)
                    a[i] = (short)f2bf(gelu_fast(bf2f((unsigned short)a8[i])));
                Acur[kc] = a;
            } else {
                const unsigned short* ap = (const unsigned short*)av + base;
                Acur[kc] = *(const short8*)(ap + kc * 32);
            }
        }
    }
    for (int p = p0; p < p1; ++p) {
        float4 Fnx[4][2];
        short8 Snx[4];
        {
            int m = (p + 1) * 64 + wave * 16 + l16; if (m >= Nrows) m = Nrows - 1;
            size_t base = (size_t)m * 128 + quad * 8;
            #pragma unroll
            for (int kc = 0; kc < 4; ++kc) {
                if (AF32) {
                    const float* ap = (const float*)av + base;
                    Fnx[kc][0] = *(const float4*)(ap + kc * 32);
                    Fnx[kc][1] = *(const float4*)(ap + kc * 32 + 4);
                } else {
                    const unsigned short* ap = (const unsigned short*)av + base;
                    Snx[kc] = *(const short8*)(ap + kc * 32);
                }
            }
        }
        int node = p * 64 + wave * 16 + l16;
        int ncl = (node < Nrows) ? node : (Nrows - 1);
        uint2 xo[8];
        if (SKIP) {
            #pragma unroll
            for (int c = 0; c < 8; ++c)
                xo[c] = *(const uint2*)(xold + (size_t)ncl * 128 + c * 16 + quad * 4);
        }
        floatx4 acc[8];
        #pragma unroll
        for (int c = 0; c < 8; ++c) acc[c] = (floatx4){0.f, 0.f, 0.f, 0.f};
        #pragma unroll
        for (int kc = 0; kc < 4; ++kc)
            #pragma unroll
            for (int c = 0; c < 8; ++c)
                acc[c] = __builtin_amdgcn_mfma_f32_16x16x32_bf16(B[c][kc], Acur[kc], acc[c], 0, 0, 0);
        if (node < Nrows) {
            #pragma unroll
            for (int c = 0; c < 8; ++c) {
                int col0 = c * 16 + quad * 4;
                float4 bv = *(const float4*)(biasB + t * 128 + col0);
                float o0 = acc[c][0] + bv.x, o1 = acc[c][1] + bv.y;
                float o2 = acc[c][2] + bv.z, o3 = acc[c][3] + bv.w;
                if (SKIP) {
                    o0 = beta * o0 + omb * __uint_as_float(xo[c].x << 16);
                    o1 = beta * o1 + omb * __uint_as_float(xo[c].x & 0xffff0000u);
                    o2 = beta * o2 + omb * __uint_as_float(xo[c].y << 16);
                    o3 = beta * o3 + omb * __uint_as_float(xo[c].y & 0xffff0000u);
                }
                o0 = fmaxf(o0, 0.f); o1 = fmaxf(o1, 0.f);
                o2 = fmaxf(o2, 0.f); o3 = fmaxf(o3, 0.f);
                uint2 u;
                u.x = (unsigned)f2bf(o0) | ((unsigned)f2bf(o1) << 16);
                u.y = (unsigned)f2bf(o2) | ((unsigned)f2bf(o3) << 16);
                *(uint2*)(out + (size_t)node * 128 + col0) = u;
            }
        }
        #pragma unroll
        for (int kc = 0; kc < 4; ++kc) {
            if (AF32) {
                float af[8] = {Fnx[kc][0].x, Fnx[kc][0].y, Fnx[kc][0].z, Fnx[kc][0].w,
                               Fnx[kc][1].x, Fnx[kc][1].y, Fnx[kc][1].z, Fnx[kc][1].w};
                short8 a;
                #pragma unroll
                for (int i = 0; i < 8; ++i) a[i] = (short)f2bf(af[i]);
                Acur[kc] = a;
            } else if (GIN) {
                short8 a;
                #pragma unroll
                for (int i = 0; i < 8; ++i)
                    a[i] = (short)f2bf(gelu_fast(bf2f((unsigned short)Snx[kc][i])));
                Acur[kc] = a;
            } else {
                Acur[kc] = Snx[kc];
            }
        }
    }
}

// ---------------- output projection: one GEMM over all 96000 rows ----------
__global__ __launch_bounds__(256, 3) void gemm_out(
    const unsigned short* __restrict__ Abf,
    const unsigned short* __restrict__ Wt,     // [64][128] bf16^T
    const float* __restrict__ bias,
    float* __restrict__ out, int Nrows)
{
    const int wave = threadIdx.x >> 6, lane = threadIdx.x & 63;
    const int quad = lane >> 4, l16 = lane & 15;
    int p0 = blockIdx.x * 4, p1 = p0 + 4;

    short8 B[4][4];
    {
        const unsigned short* wb = Wt + (size_t)l16 * 128 + quad * 8;
        #pragma unroll
        for (int c = 0; c < 4; ++c)
            #pragma unroll
            for (int kc = 0; kc < 4; ++kc)
                B[c][kc] = *(const short8*)(wb + (size_t)c * 2048 + kc * 32);
    }
    float4 bv[4];
    #pragma unroll
    for (int c = 0; c < 4; ++c) bv[c] = *(const float4*)(bias + c * 16 + quad * 4);

    short8 Acur[4];
    {
        int m = p0 * 64 + wave * 16 + l16; if (m >= Nrows) m = Nrows - 1;
        const unsigned short* ap = Abf + (size_t)m * 128 + quad * 8;
        #pragma unroll
        for (int kc = 0; kc < 4; ++kc) Acur[kc] = *(const short8*)(ap + kc * 32);
    }
    for (int p = p0; p < p1; ++p) {
        short8 Anx[4];
        {
            int m = (p + 1) * 64 + wave * 16 + l16; if (m >= Nrows) m = Nrows - 1;
            const unsigned short* ap = Abf + (size_t)m * 128 + quad * 8;
            #pragma unroll
            for (int kc = 0; kc < 4; ++kc) Anx[kc] = *(const short8*)(ap + kc * 32);
        }
        floatx4 acc[4];
        #pragma unroll
        for (int c = 0; c < 4; ++c) acc[c] = (floatx4){0.f, 0.f, 0.f, 0.f};
        #pragma unroll
        for (int kc = 0; kc < 4; ++kc)
            #pragma unroll
            for (int c = 0; c < 4; ++c)
                acc[c] = __builtin_amdgcn_mfma_f32_16x16x32_bf16(B[c][kc], Acur[kc], acc[c], 0, 0, 0);
        int node = p * 64 + wave * 16 + l16;
        if (node < Nrows) {
            #pragma unroll
            for (int c = 0; c < 4; ++c) {
                float4 o;
                o.x = acc[c][0] + bv[c].x; o.y = acc[c][1] + bv[c].y;
                o.z = acc[c][2] + bv[c].z; o.w = acc[c][3] + bv[c].w;
                *(float4*)(out + (size_t)node * 64 + c * 16 + quad * 4) = o;
            }
        }
        #pragma unroll
        for (int kc = 0; kc < 4; ++kc) Acur[kc] = Anx[kc];
    }
}

// ------------------- fused weight prep (4 kernels -> 1) ---------------------
// blocks: [0,768) qpack / [768,1792) fold_rel / [1792,2944) w9 / [2944,3072) owt
__global__ __launch_bounds__(128) void prep_all(
    const float* __restrict__ qw, const float* __restrict__ qb,
    const float* __restrict__ kw, const float* __restrict__ kb,
    const float* __restrict__ vw, const float* __restrict__ vb,
    const float* __restrict__ a_rel, const float* __restrict__ m_rel,
    const float* __restrict__ lin_w, const float* __restrict__ aw,
    const float* __restrict__ ow,
    unsigned short* __restrict__ Wpack, float* __restrict__ bpack,
    unsigned short* __restrict__ lwt, unsigned short* __restrict__ awt,
    unsigned short* __restrict__ owt)
{
    const int pre[3] = {0, 49152, 131072};
    const int preB[3] = {0, 384, 1024};
    int b = blockIdx.x;
    if (b < 768) {
        int n = threadIdx.x;
        int k = b & 127, r = b >> 7, t = r % 3, l = r / 3;
        unsigned short* Wp = Wpack + (size_t)l * 180224 + pre[t];
        Wp[(size_t)n * 128 + k] = f2bf(qw[(size_t)(l * 3 + t) * 16384 + (size_t)k * 128 + n]);
        if (k == 0) bpack[l * 1408 + preB[t] + n] = qb[(l * 3 + t) * 128 + n];
    } else if (b < 1792) {
        const int SIv[4] = {0, 1, 1, 2};
        const int SLOT[4] = {0, 0, 1, 0};
        int bb = b - 768;
        int hf = threadIdx.x, h = hf >> 4, f = hf & 15;
        int c = bb & 127, et = (bb >> 7) & 3, l = bb >> 9;
        int si = SIv[et];
        const float* kwp  = kw + (size_t)(l * 3 + si) * 16384;
        const float* vwp  = vw + (size_t)(l * 3 + si) * 16384;
        const float* kbp  = kb + (size_t)(l * 3 + si) * 128;
        const float* vbp  = vb + (size_t)(l * 3 + si) * 128;
        const float* arel = a_rel + (size_t)(l * 4 + et) * 2048;
        const float* mrel = m_rel + (size_t)(l * 4 + et) * 2048;
        float sk = 0.f, sv = 0.f;
        #pragma unroll
        for (int d = 0; d < 16; ++d) {
            float ar = arel[(h * 16 + d) * 16 + f];
            float mr = mrel[(h * 16 + d) * 16 + f];
            sk = fmaf(kwp[c * 128 + h * 16 + d], ar, sk);
            sv = fmaf(vwp[c * 128 + h * 16 + d], mr, sv);
        }
        int rowoff = 128 + 256 * SLOT[et];
        unsigned short* Wp = Wpack + (size_t)l * 180224 + pre[si];
        Wp[(size_t)(rowoff + hf) * 128 + c]       = f2bf(sk);
        Wp[(size_t)(rowoff + 128 + hf) * 128 + c] = f2bf(sv);
        if (c == 0) {
            float bk = 0.f, bvv = 0.f;
            #pragma unroll
            for (int d = 0; d < 16; ++d) {
                bk  = fmaf(kbp[h * 16 + d], arel[(h * 16 + d) * 16 + f], bk);
                bvv = fmaf(vbp[h * 16 + d], mrel[(h * 16 + d) * 16 + f], bvv);
            }
            float* bp = bpack + l * 1408 + preB[si];
            bp[rowoff + hf]       = bk;
            bp[rowoff + 128 + hf] = bvv;
        }
    } else if (b < 2944) {
        int bb = b - 1792;
        int n = threadIdx.x, k = bb & 127, mi = bb >> 7;
        const float* w; unsigned short* wt; int m;
        if (mi < 3) { w = lin_w; wt = lwt; m = mi; }
        else        { w = aw;    wt = awt; m = mi - 3; }
        wt[(size_t)m * 16384 + (size_t)n * 128 + k] =
            f2bf(w[(size_t)m * 16384 + (size_t)k * 128 + n]);
    } else {
        int k = b - 2944, n = threadIdx.x;
        if (n < 64) owt[(size_t)n * 128 + k] = f2bf(ow[(size_t)k * 64 + n]);
    }
}

// ------------------------- CSR build (fused across edge types) --------------
__global__ __launch_bounds__(256) void hist_all(
    const int* __restrict__ d0, const int* __restrict__ d1,
    const int* __restrict__ d2, const int* __restrict__ d3,
    int* __restrict__ deg4)
{
    const int Ev[4] = {200000, 300000, 200000, 100000};
    int et = blockIdx.y;
    int e = blockIdx.x * 256 + threadIdx.x;
    if (e >= Ev[et]) return;
    const int* d = et == 0 ? d0 : et == 1 ? d1 : et == 2 ? d2 : d3;
    atomicAdd(&deg4[et * 60000 + d[e]], 1);
}

// computes per-tile rowptr prefix AND zeroes deg4 back for fill's cursors
__global__ __launch_bounds__(256) void scan_tile_all(
    int* __restrict__ deg4,
    int* __restrict__ r0, int* __restrict__ r1, int* __restrict__ r2, int* __restrict__ r3,
    int* __restrict__ tsum4)
{
    const int Ndv[4] = {60000, 60000, 6000, 30000};
    __shared__ int ls[256];
    int et = blockIdx.y;
    int n = Ndv[et];
    int* deg = deg4 + et * 60000;
    int* rowptr = et == 0 ? r0 : et == 1 ? r1 : et == 2 ? r2 : r3;
    int b = blockIdx.x, tid = threadIdx.x;
    int base = b * 1024 + tid * 4;
    int v0 = 0, v1 = 0, v2 = 0, v3 = 0;
    if (base + 3 < n) {
        int4 t = *(const int4*)(deg + base);
        v0 = t.x; v1 = t.y; v2 = t.z; v3 = t.w;
        *(int4*)(deg + base) = make_int4(0, 0, 0, 0);
    } else {
        if (base + 0 < n) { v0 = deg[base + 0]; deg[base + 0] = 0; }
        if (base + 1 < n) { v1 = deg[base + 1]; deg[base + 1] = 0; }
        if (base + 2 < n) { v2 = deg[base + 2]; deg[base + 2] = 0; }
        if (base + 3 < n) { v3 = deg[base + 3]; deg[base + 3] = 0; }
    }
    int s = v0 + v1 + v2 + v3;
    ls[tid] = s;
    __syncthreads();
    #pragma unroll
    for (int off = 1; off < 256; off <<= 1) {
        int t = (tid >= off) ? ls[tid - off] : 0;
        __syncthreads();
        ls[tid] += t;
        __syncthreads();
    }
    int run = ls[tid] - s;
    int o0 = run; run += v0;
    int o1 = run; run += v1;
    int o2 = run; run += v2;
    int o3 = run;
    if (base + 3 < n) {
        *(int4*)(rowptr + base) = make_int4(o0, o1, o2, o3);
    } else {
        if (base + 0 < n) rowptr[base + 0] = o0;
        if (base + 1 < n) rowptr[base + 1] = o1;
        if (base + 2 < n) rowptr[base + 2] = o2;
    }
    if (tid == 255) tsum4[et * 64 + b] = ls[255];
}

// adds tile-prefix (computed from raw per-tile sums in LDS) + writes total
__global__ __launch_bounds__(256) void scan_add_all(
    int* __restrict__ r0, int* __restrict__ r1, int* __restrict__ r2, int* __restrict__ r3,
    const int* __restrict__ tsum4)
{
    const int Ndv[4] = {60000, 60000, 6000, 30000};
    __shared__ int ts[64];
    int et = blockIdx.y;
    int n = Ndv[et];
    int* rowptr = et == 0 ? r0 : et == 1 ? r1 : et == 2 ? r2 : r3;
    int tid = threadIdx.x;
    if (tid < 64) ts[tid] = tsum4[et * 64 + tid];
    __syncthreads();
    int i = blockIdx.x * 256 + tid;
    int tile = i >> 10;
    int pre = 0;
    for (int j = 0; j < tile; ++j) pre += ts[j];
    if (i < n) rowptr[i] += pre;
    if (blockIdx.x == 0 && tid == 0) {
        int nt = (n + 1023) >> 10, tot = 0;
        for (int j = 0; j < nt; ++j) tot += ts[j];
        rowptr[n] = tot;
    }
}

__global__ __launch_bounds__(256) void fill_all(
    const int* __restrict__ s0, const int* __restrict__ d0,
    const int* __restrict__ s1, const int* __restrict__ d1,
    const int* __restrict__ s2, const int* __restrict__ d2,
    const int* __restrict__ s3, const int* __restrict__ d3,
    const int* __restrict__ r0, const int* __restrict__ r1,
    const int* __restrict__ r2, const int* __restrict__ r3,
    int* __restrict__ deg4,
    int* __restrict__ c0, int* __restrict__ c1, int* __restrict__ c2, int* __restrict__ c3)
{
    const int Ev[4] = {200000, 300000, 200000, 100000};
    int et = blockIdx.y;
    int e = blockIdx.x * 256 + threadIdx.x;
    if (e >= Ev[et]) return;
    const int* src = et == 0 ? s0 : et == 1 ? s1 : et == 2 ? s2 : s3;
    const int* dst = et == 0 ? d0 : et == 1 ? d1 : et == 2 ? d2 : d3;
    const int* rowptr = et == 0 ? r0 : et == 1 ? r1 : et == 2 ? r2 : r3;
    int* csr = et == 0 ? c0 : et == 1 ? c1 : et == 2 ? c2 : c3;
    int d = dst[e];
    int pos = atomicAdd(&deg4[et * 60000 + d], 1);
    csr[rowptr[d] + pos] = src[e];
}

// --------------- merged gather-side attention (all 4 edge types) ------------
// Depth-2 paired pipeline; defer-max (THR=8, exact).
__device__ __forceinline__ void attn_edge(
    uint4 k0, uint4 k1, uint4 v0, uint4 v1,
    const float* qf, float ph, float& m, float& l, float* o)
{
    float kf[16];
    up8(k0, kf); up8(k1, kf + 8);
    float a = 0.f;
    #pragma unroll
    for (int i = 0; i < 16; ++i) a = fmaf(qf[i], kf[i], a);
    a *= ph;
    float d = a - m;
    if (d > 8.f) {
        float sc = __expf(-d);
        l *= sc;
        #pragma unroll
        for (int i = 0; i < 16; ++i) o[i] *= sc;
        m = a; d = 0.f;
    }
    float w = __expf(d);
    l += w;
    float vf[16];
    up8(v0, vf); up8(v1, vf + 8);
    #pragma unroll
    for (int i = 0; i < 16; ++i) o[i] = fmaf(w, vf[i], o[i]);
}

__device__ __forceinline__ void attn_run(
    const int* __restrict__ csr, int beg, int end,
    const unsigned short* __restrict__ kbase, int ld,
    const float* qf, float ph, float& m, float& l, float* o)
{
    int n = end - beg;
    if (n <= 0) return;
    const uint4* pA = (const uint4*)(kbase + (size_t)csr[beg] * ld);
    uint4 A0 = pA[0], A1 = pA[1], A2 = pA[16], A3 = pA[17];
    uint4 B0 = A0, B1 = A1, B2 = A2, B3 = A3;
    if (n > 1) {
        const uint4* pB = (const uint4*)(kbase + (size_t)csr[beg + 1] * ld);
        B0 = pB[0]; B1 = pB[1]; B2 = pB[16]; B3 = pB[17];
    }
    int j = beg;
    for (; j + 3 < end; j += 2) {
        const uint4* pC = (const uint4*)(kbase + (size_t)csr[j + 2] * ld);
        const uint4* pD = (const uint4*)(kbase + (size_t)csr[j + 3] * ld);
        uint4 C0 = pC[0], C1 = pC[1], C2 = pC[16], C3 = pC[17];
        uint4 D0 = pD[0], D1 = pD[1], D2 = pD[16], D3 = pD[17];
        float kf0[16], kf1[16];
        up8(A0, kf0); up8(A1, kf0 + 8);
        up8(B0, kf1); up8(B1, kf1 + 8);
        float a0 = 0.f, a1 = 0.f;
        #pragma unroll
        for (int i = 0; i < 16; ++i) {
            a0 = fmaf(qf[i], kf0[i], a0);
            a1 = fmaf(qf[i], kf1[i], a1);
        }
        a0 *= ph; a1 *= ph;
        float hi = fmaxf(a0, a1);
        float d = hi - m;
        if (d > 8.f) {
            float sc = __expf(-d);
            l *= sc;
            #pragma unroll
            for (int i = 0; i < 16; ++i) o[i] *= sc;
            m = hi;
        }
        float w0 = __expf(a0 - m), w1 = __expf(a1 - m);
        l += w0 + w1;
        float vf0[16], vf1[16];
        up8(A2, vf0); up8(A3, vf0 + 8);
        up8(B2, vf1); up8(B3, vf1 + 8);
        #pragma unroll
        for (int i = 0; i < 16; ++i)
            o[i] = fmaf(w1, vf1[i], fmaf(w0, vf0[i], o[i]));
        A0 = C0; A1 = C1; A2 = C2; A3 = C3;
        B0 = D0; B1 = D1; B2 = D2; B3 = D3;
    }
    int rem = end - j;                      // 1..3
    attn_edge(A0, A1, A2, A3, qf, ph, m, l, o);
    if (rem >= 2) attn_edge(B0, B1, B2, B3, qf, ph, m, l, o);
    if (rem == 3) {
        const uint4* pC = (const uint4*)(kbase + (size_t)csr[j + 2] * ld);
        attn_edge(pC[0], pC[1], pC[16], pC[17], qf, ph, m, l, o);
    }
}

// merge partial online-softmax state across lanes (xor st)
__device__ __forceinline__ void merge_sm(float& m, float& l, float* o, int st)
{
    float mp = __shfl_xor(m, st);
    float lp = __shfl_xor(l, st);
    float mn = fmaxf(m, mp);
    float sc  = (l  > 0.f) ? __expf(m  - mn) : 0.f;
    float scp = (lp > 0.f) ? __expf(mp - mn) : 0.f;
    l = l * sc + lp * scp;
    #pragma unroll
    for (int i = 0; i < 16; ++i) {
        float op = __shfl_xor(o[i], st);
        o[i] = o[i] * sc + op * scp;
    }
    m = mn;
}

// grid: [0,3750) road (et0 & et1 on parallel lanes, 16 lanes/node) /
//       [3750,4500) region (et2, 4-way split) / [4500,5438) poi (et3 serial)
__global__ __launch_bounds__(256) void agg_all(
    const int* __restrict__ rp0, const int* __restrict__ cs0,
    const int* __restrict__ rp1, const int* __restrict__ cs1,
    const int* __restrict__ rp2, const int* __restrict__ cs2,
    const int* __restrict__ rp3, const int* __restrict__ cs3,
    const unsigned short* __restrict__ P0, const unsigned short* __restrict__ P1,
    const unsigned short* __restrict__ P2,
    const float* __restrict__ prl,      // p_rel + l*32
    unsigned short* __restrict__ num)
{
    int gb = blockIdx.x, tid = threadIdx.x;
    float qf[16], o[16], r[16];
    if (gb < 3750) {
        // ---- road: lane = (node, h, half); half0 runs et0, half1 runs et1,
        //      FULL runs in parallel; combine normalized partials via xor-8.
        int t = gb * 256 + tid;            // < 960000 exactly
        int node = t >> 4, h = t & 7, half = (t >> 3) & 1;
        const uint4* qp = (const uint4*)(P1 + (size_t)node * 640 + h * 16);
        up8(qp[0], qf); up8(qp[1], qf + 8);
        const int* csr = half ? cs1 : cs0;
        const int* rp  = half ? rp1 : rp0;
        const unsigned short* kb = half ? (P1 + 128 + h * 16) : (P0 + 128 + h * 16);
        int ld = half ? 640 : 384;
        float ph = prl[(half ? 8 : 0) + h] * 0.25f;
        float m = -INFINITY, l = 0.f;
        #pragma unroll
        for (int i = 0; i < 16; ++i) o[i] = 0.f;
        attn_run(csr, rp[node], rp[node + 1], kb, ld, qf, ph, m, l, o);
        float inv = 1.f / (l + 1e-16f);
        #pragma unroll
        for (int i = 0; i < 16; ++i) r[i] = inv * o[i];
        #pragma unroll
        for (int i = 0; i < 16; ++i) r[i] += __shfl_xor(r[i], 8);
        if (half) return;
        uint4* np = (uint4*)(num + (size_t)(30000 + node) * 128 + h * 16);
        np[0] = pk8(r); np[1] = pk8(r + 8);
    } else if (gb < 4500) {
        // ---- region: et2 (road src), 4-way edge split + shuffle merge ----
        int t = (gb - 3750) * 256 + tid;   // < 192000 exactly
        int node = t >> 5, h = t & 7, sub = (t >> 3) & 3;
        int beg0 = rp2[node], end0 = rp2[node + 1];
        int n = end0 - beg0;
        int beg = beg0 + ((n * sub) >> 2);
        int end = beg0 + ((n * (sub + 1)) >> 2);
        const uint4* qp = (const uint4*)(P2 + (size_t)node * 384 + h * 16);
        up8(qp[0], qf); up8(qp[1], qf + 8);
        float m = -INFINITY, l = 0.f;
        #pragma unroll
        for (int i = 0; i < 16; ++i) o[i] = 0.f;
        attn_run(cs2, beg, end, P1 + 384 + h * 16, 640,
                 qf, prl[16 + h] * 0.25f, m, l, o);
        merge_sm(m, l, o, 8);
        merge_sm(m, l, o, 16);
        if (sub) return;
        float inv = 1.f / (l + 1e-16f);
        #pragma unroll
        for (int i = 0; i < 16; ++i) r[i] = inv * o[i];
        uint4* np = (uint4*)(num + (size_t)(90000 + node) * 128 + h * 16);
        np[0] = pk8(r); np[1] = pk8(r + 8);
    } else {
        // ---- poi: et3 (region src), serial run ----
        int t = (gb - 4500) * 256 + tid;
        if (t >= 240000) return;
        int node = t >> 3, h = t & 7;
        const uint4* qp = (const uint4*)(P0 + (size_t)node * 384 + h * 16);
        up8(qp[0], qf); up8(qp[1], qf + 8);
        float m = -INFINITY, l = 0.f;
        #pragma unroll
        for (int i = 0; i < 16; ++i) o[i] = 0.f;
        attn_run(cs3, rp3[node], rp3[node + 1], P2 + 128 + h * 16, 384,
                 qf, prl[24 + h] * 0.25f, m, l, o);
        float inv = 1.f / (l + 1e-16f);
        #pragma unroll
        for (int i = 0; i < 16; ++i) r[i] = inv * o[i];
        uint4* np = (uint4*)(num + (size_t)node * 128 + h * 16);
        np[0] = pk8(r); np[1] = pk8(r + 8);
    }
}

extern "C" void kernel_launch(void* const* d_in, const int* in_sizes, int n_in,
                              void* d_out, int out_size, void* d_ws, size_t ws_size,
                              hipStream_t stream)
{
    (void)in_sizes; (void)n_in; (void)out_size; (void)ws_size;

    const float* xin[3] = {(const float*)d_in[0], (const float*)d_in[1], (const float*)d_in[2]};
    const int* esrc[4] = {(const int*)d_in[3], (const int*)d_in[5], (const int*)d_in[7], (const int*)d_in[9]};
    const int* edst[4] = {(const int*)d_in[4], (const int*)d_in[6], (const int*)d_in[8], (const int*)d_in[10]};
    const float* lin_w = (const float*)d_in[11];
    const float* lin_b = (const float*)d_in[12];
    const float* kw = (const float*)d_in[13];
    const float* qw = (const float*)d_in[14];
    const float* vw = (const float*)d_in[15];
    const float* aw = (const float*)d_in[16];
    const float* kb = (const float*)d_in[17];
    const float* qb = (const float*)d_in[18];
    const float* vb = (const float*)d_in[19];
    const float* ab = (const float*)d_in[20];
    const float* a_rel = (const float*)d_in[21];
    const float* m_rel = (const float*)d_in[22];
    const float* p_rel = (const float*)d_in[23];
    const float* skip  = (const float*)d_in[24];
    const float* out_w = (const float*)d_in[25];
    const float* out_b = (const float*)d_in[26];

    // workspace (float-index units; ~39.9M floats = 160 MB)
    float* ws = (float*)d_ws;
    unsigned short* num   = (unsigned short*)ws;                // 12,288,000 h
    unsigned short* xs_bf = (unsigned short*)(ws + 6144000);    // 12,288,000 h
    unsigned short* proj  = (unsigned short*)(ws + 12288000);   // 52,224,000 h
    unsigned short* Wpack = (unsigned short*)(ws + 38400000);   // 360,448 h
    unsigned short* lwt   = (unsigned short*)(ws + 38580224);   // 49,152 h
    unsigned short* awt   = (unsigned short*)(ws + 38604800);   // 98,304 h
    unsigned short* owt   = (unsigned short*)(ws + 38653952);   // 8,192 h
    float*          bpack = ws + 38658048;                      // 2,816 f
    int*            deg4  = (int*)(ws + 38660864);              // 240,000
    int*            tsum4 = (int*)(ws + 38900864);              // 256
    int* rp[4];
    rp[0] = (int*)(ws + 38901120);                              // 60,008
    rp[1] = (int*)(ws + 38961128);
    rp[2] = (int*)(ws + 39021136);                              // 6,008
    rp[3] = (int*)(ws + 39027144);                              // 30,008
    int* cs[4];
    cs[0] = (int*)(ws + 39057152);                              // 200,000
    cs[1] = (int*)(ws + 39257152);                              // 300,000
    cs[2] = (int*)(ws + 39557152);                              // 200,000
    cs[3] = (int*)(ws + 39757152);                              // 100,000

    unsigned short* P[3];
    P[0] = proj;
    P[1] = proj + (size_t)30000 * 384;
    P[2] = proj + (size_t)30000 * 384 + (size_t)60000 * 640;

    dim3 blk(256);

    // ---- CSR build, fused across edge types (4 kernels + 1 memset) ----
    hipMemsetAsync(deg4, 0, 960000, stream);
    hist_all<<<dim3(1172, 4), blk, 0, stream>>>(edst[0], edst[1], edst[2], edst[3], deg4);
    scan_tile_all<<<dim3(59, 4), blk, 0, stream>>>(deg4, rp[0], rp[1], rp[2], rp[3], tsum4);
    scan_add_all<<<dim3(235, 4), blk, 0, stream>>>(rp[0], rp[1], rp[2], rp[3], tsum4);
    fill_all<<<dim3(1172, 4), blk, 0, stream>>>(
        esrc[0], edst[0], esrc[1], edst[1], esrc[2], edst[2], esrc[3], edst[3],
        rp[0], rp[1], rp[2], rp[3], deg4, cs[0], cs[1], cs[2], cs[3]);

    // ---- weight prep (fused) ----
    prep_all<<<dim3(3072), dim3(128), 0, stream>>>(
        qw, qb, kw, kb, vw, vb, a_rel, m_rel, lin_w, aw, out_w,
        Wpack, bpack, lwt, awt, owt);

    // ---- input linear + relu -> xs_bf (fused across types) ----
    gemm_node<true, false, false><<<dim3(751), blk, 0, stream>>>(
        xin[0], xin[1], xin[2], lwt, lin_b, nullptr, nullptr, xs_bf);

    for (int l = 0; l < 2; ++l) {
        // packed projection per node type: [q | ka|mv ...], one fused launch
        gemm_proj_all<<<dim3(1601), blk, 0, stream>>>(
            xs_bf, Wpack + (size_t)l * 180224, bpack + l * 1408, proj);

        // merged aggregation: all 4 edge types in one launch
        agg_all<<<dim3(5438), blk, 0, stream>>>(
            rp[0], cs[0], rp[1], cs[1], rp[2], cs[2], rp[3], cs[3],
            P[0], P[1], P[2], p_rel + (size_t)l * 32, num);

        // node update (fused across types)
        gemm_node<false, true, true><<<dim3(751), blk, 0, stream>>>(
            num, num + (size_t)30000 * 128, num + (size_t)90000 * 128,
            awt + (size_t)l * 3 * 16384, ab + (size_t)l * 3 * 128,
            xs_bf, skip + l * 3, xs_bf);
    }

    // ---- output projection: single GEMM over all 96000 rows ----
    gemm_out<<<dim3(375), blk, 0, stream>>>(
        xs_bf, owt, out_b, (float*)d_out, 96000);
}

// Round 9
// 567.544 us; speedup vs baseline: 1.0336x; 1.0336x over previous
//
#include <hip/hip_runtime.h>
#include <cstddef>
#include <cstdint>

// ---------------------------------------------------------------------------
// HGT forward for MI355X. C=128, H=8, D=16, OUT=64, L=2
//   NN = {30000, 60000, 6000}, NE = {200000, 300000, 200000, 100000}
//   ETS = {(0,1),(1,1),(1,2),(2,0)}
// Round-18 changes:
//  * gemm_proj_all REVERTED to r7 config (cp-major, 8 panels, 803 blocks).
//    r8's rb-major spread same-A blocks across XCDs (private L2s -> FETCH
//    52->65 MB) and 4-panel halved W amortization (occ 17%, 55->66.5us).
//    Lesson: proj is latency-bound (bytes floor 24us vs 55 actual) -- keep
//    max panels/block.
//  * gemm_node: panels/block 2->4 (751->377 blocks) -- same amortization
//    logic applied where it IS the bottleneck: W-resident setup (16KB, 32
//    L2-latency loads) was paid per 128 rows; now per 256 rows.
// ---------------------------------------------------------------------------

typedef __attribute__((ext_vector_type(8))) short short8;   // 8 x bf16
typedef __attribute__((ext_vector_type(4))) float floatx4;

__device__ __forceinline__ float gelu_fast(float x) {
    float u = 1.5957691216057308f * x * (1.0f + 0.044715f * x * x);
    return x / (1.0f + __expf(-u));
}

__device__ __forceinline__ unsigned short f2bf(float f) {   // RNE fp32->bf16
    unsigned u = __float_as_uint(f);
    u += 0x7fffu + ((u >> 16) & 1);
    return (unsigned short)(u >> 16);
}

__device__ __forceinline__ float bf2f(unsigned short h) {
    return __uint_as_float((unsigned)h << 16);
}

__device__ __forceinline__ void up8(uint4 u, float* f) {    // 8 bf16 -> 8 fp32
    f[0] = __uint_as_float(u.x << 16); f[1] = __uint_as_float(u.x & 0xffff0000u);
    f[2] = __uint_as_float(u.y << 16); f[3] = __uint_as_float(u.y & 0xffff0000u);
    f[4] = __uint_as_float(u.z << 16); f[5] = __uint_as_float(u.z & 0xffff0000u);
    f[6] = __uint_as_float(u.w << 16); f[7] = __uint_as_float(u.w & 0xffff0000u);
}

__device__ __forceinline__ uint4 pk8(const float* f) {      // 8 fp32 -> 8 bf16
    uint4 u;
    u.x = (unsigned)f2bf(f[0]) | ((unsigned)f2bf(f[1]) << 16);
    u.y = (unsigned)f2bf(f[2]) | ((unsigned)f2bf(f[3]) << 16);
    u.z = (unsigned)f2bf(f[4]) | ((unsigned)f2bf(f[5]) << 16);
    u.w = (unsigned)f2bf(f[6]) | ((unsigned)f2bf(f[7]) << 16);
    return u;
}

// ---------------- W-resident streaming MFMA GEMM (packed proj) -------------
// cp-major (r7 config): road [0,590)=5cp x 118rb / poi [590,767)=3cp x 59 /
// region [767,803)=3cp x 12. 8 panels (512 rows) per block.
__global__ __launch_bounds__(256, 2) void gemm_proj_all(
    const unsigned short* __restrict__ xs_bf,
    const unsigned short* __restrict__ Wl,     // Wpack + l*180224
    const float* __restrict__ bl,              // bpack + l*1408
    unsigned short* __restrict__ proj)
{
    const int    NN_[3]  = {30000, 60000, 6000};
    const int    NPAN[3] = {469, 938, 94};
    const int    OFFr[3] = {0, 30000, 90000};
    const int    WOFF[3] = {0, 49152, 131072};
    const int    BOFF[3] = {0, 384, 1024};
    const size_t POFF[3] = {0, 11520000u, 49920000u};
    const int    LDO[3]  = {384, 640, 384};

    int b = blockIdx.x, t, cp, rb;
    if (b < 590)      { t = 1; cp = b / 118; rb = b - cp * 118; }
    else if (b < 767) { int lb = b - 590; t = 0; cp = lb / 59; rb = lb - cp * 59; }
    else              { int lb = b - 767; t = 2; cp = lb / 12; rb = lb - cp * 12; }
    int p0 = rb * 8, p1 = p0 + 8;
    if (p1 > NPAN[t]) p1 = NPAN[t];

    const unsigned short* Abf = xs_bf + (size_t)OFFr[t] * 128;
    const unsigned short* Wt  = Wl + WOFF[t];
    const float* bias = bl + BOFF[t] + cp * 128;
    unsigned short* outbf = proj + POFF[t];
    const int ldo = LDO[t], Nrows = NN_[t];

    const int wave = threadIdx.x >> 6, lane = threadIdx.x & 63;
    const int quad = lane >> 4, l16 = lane & 15;

    short8 B[2][4][4];
    {
        const unsigned short* wb = Wt + (size_t)(cp * 128 + l16) * 128 + quad * 8;
        #pragma unroll
        for (int T = 0; T < 2; ++T)
            #pragma unroll
            for (int c = 0; c < 4; ++c)
                #pragma unroll
                for (int kc = 0; kc < 4; ++kc)
                    B[T][c][kc] = *(const short8*)(wb + (size_t)(T * 64 + c * 16) * 128 + kc * 32);
    }
    float4 bv[2][4];
    #pragma unroll
    for (int T = 0; T < 2; ++T)
        #pragma unroll
        for (int c = 0; c < 4; ++c)
            bv[T][c] = *(const float4*)(bias + T * 64 + c * 16 + quad * 4);

    short8 Acur[4];
    {
        int m = p0 * 64 + wave * 16 + l16; if (m >= Nrows) m = Nrows - 1;
        const unsigned short* ap = Abf + (size_t)m * 128 + quad * 8;
        #pragma unroll
        for (int kc = 0; kc < 4; ++kc) Acur[kc] = *(const short8*)(ap + kc * 32);
    }
    for (int p = p0; p < p1; ++p) {
        short8 Anx[4];
        {
            int m = (p + 1) * 64 + wave * 16 + l16; if (m >= Nrows) m = Nrows - 1;
            const unsigned short* ap = Abf + (size_t)m * 128 + quad * 8;
            #pragma unroll
            for (int kc = 0; kc < 4; ++kc) Anx[kc] = *(const short8*)(ap + kc * 32);
        }
        floatx4 acc[2][4];
        #pragma unroll
        for (int T = 0; T < 2; ++T)
            #pragma unroll
            for (int c = 0; c < 4; ++c) acc[T][c] = (floatx4){0.f, 0.f, 0.f, 0.f};
        #pragma unroll
        for (int kc = 0; kc < 4; ++kc)
            #pragma unroll
            for (int T = 0; T < 2; ++T)
                #pragma unroll
                for (int c = 0; c < 4; ++c)
                    acc[T][c] = __builtin_amdgcn_mfma_f32_16x16x32_bf16(B[T][c][kc], Acur[kc], acc[T][c], 0, 0, 0);
        int node = p * 64 + wave * 16 + l16;
        if (node < Nrows) {
            unsigned short* op = outbf + (size_t)node * ldo + cp * 128 + quad * 4;
            #pragma unroll
            for (int T = 0; T < 2; ++T)
                #pragma unroll
                for (int c = 0; c < 4; ++c) {
                    uint2 u;
                    u.x = (unsigned)f2bf(acc[T][c][0] + bv[T][c].x) |
                          ((unsigned)f2bf(acc[T][c][1] + bv[T][c].y) << 16);
                    u.y = (unsigned)f2bf(acc[T][c][2] + bv[T][c].z) |
                          ((unsigned)f2bf(acc[T][c][3] + bv[T][c].w) << 16);
                    *(uint2*)(op + T * 64 + c * 16) = u;
                }
        }
        #pragma unroll
        for (int kc = 0; kc < 4; ++kc) Acur[kc] = Anx[kc];
    }
}

// ---------------- fused-by-type node GEMM (input linear / node update) -----
// 4 panels (256 rows) per block: poi [0,118) / road [118,353) / region
// [353,377).
template<bool AF32, bool GIN, bool SKIP>
__global__ __launch_bounds__(256, 2) void gemm_node(
    const void* __restrict__ a0v, const void* __restrict__ a1v, const void* __restrict__ a2v,
    const unsigned short* __restrict__ WtB, const float* __restrict__ biasB,
    const unsigned short* __restrict__ xoldB, const float* __restrict__ skipB,
    unsigned short* __restrict__ outB)
{
    const int TN[3]   = {30000, 60000, 6000};
    const int NPAN[3] = {469, 938, 94};
    const int TOFF[3] = {0, 30000, 90000};
    int b = blockIdx.x, t, rb;
    if (b < 118)      { t = 0; rb = b; }
    else if (b < 353) { t = 1; rb = b - 118; }
    else              { t = 2; rb = b - 353; }
    int p0 = rb * 4, p1 = p0 + 4;
    if (p1 > NPAN[t]) p1 = NPAN[t];
    int Nrows = TN[t];
    const void* av = (t == 0) ? a0v : (t == 1) ? a1v : a2v;
    const unsigned short* xold = xoldB + (size_t)TOFF[t] * 128;
    unsigned short* out = outB + (size_t)TOFF[t] * 128;

    const int wave = threadIdx.x >> 6, lane = threadIdx.x & 63;
    const int quad = lane >> 4, l16 = lane & 15;

    short8 B[8][4];
    {
        const unsigned short* wb = WtB + (size_t)t * 16384 + (size_t)l16 * 128 + quad * 8;
        #pragma unroll
        for (int c = 0; c < 8; ++c)
            #pragma unroll
            for (int kc = 0; kc < 4; ++kc)
                B[c][kc] = *(const short8*)(wb + (size_t)c * 2048 + kc * 32);
    }
    float beta = 0.f, omb = 0.f;
    if (SKIP) { beta = 1.0f / (1.0f + __expf(-skipB[t])); omb = 1.0f - beta; }

    short8 Acur[4];
    {
        int m = p0 * 64 + wave * 16 + l16; if (m >= Nrows) m = Nrows - 1;
        size_t base = (size_t)m * 128 + quad * 8;
        #pragma unroll
        for (int kc = 0; kc < 4; ++kc) {
            if (AF32) {
                const float* ap = (const float*)av + base;
                float4 f0 = *(const float4*)(ap + kc * 32);
                float4 f1 = *(const float4*)(ap + kc * 32 + 4);
                float af[8] = {f0.x, f0.y, f0.z, f0.w, f1.x, f1.y, f1.z, f1.w};
                short8 a;
                #pragma unroll
                for (int i = 0; i < 8; ++i) a[i] = (short)f2bf(af[i]);
                Acur[kc] = a;
            } else if (GIN) {
                const unsigned short* ap = (const unsigned short*)av + base;
                short8 a8 = *(const short8*)(ap + kc * 32);
                short8 a;
                #pragma unroll
                for (int i = 0; i < 8; ++i)
                    a[i] = (short)f2bf(gelu_fast(bf2f((unsigned short)a8[i])));
                Acur[kc] = a;
            } else {
                const unsigned short* ap = (const unsigned short*)av + base;
                Acur[kc] = *(const short8*)(ap + kc * 32);
            }
        }
    }
    for (int p = p0; p < p1; ++p) {
        float4 Fnx[4][2];
        short8 Snx[4];
        {
            int m = (p + 1) * 64 + wave * 16 + l16; if (m >= Nrows) m = Nrows - 1;
            size_t base = (size_t)m * 128 + quad * 8;
            #pragma unroll
            for (int kc = 0; kc < 4; ++kc) {
                if (AF32) {
                    const float* ap = (const float*)av + base;
                    Fnx[kc][0] = *(const float4*)(ap + kc * 32);
                    Fnx[kc][1] = *(const float4*)(ap + kc * 32 + 4);
                } else {
                    const unsigned short* ap = (const unsigned short*)av + base;
                    Snx[kc] = *(const short8*)(ap + kc * 32);
                }
            }
        }
        int node = p * 64 + wave * 16 + l16;
        int ncl = (node < Nrows) ? node : (Nrows - 1);
        uint2 xo[8];
        if (SKIP) {
            #pragma unroll
            for (int c = 0; c < 8; ++c)
                xo[c] = *(const uint2*)(xold + (size_t)ncl * 128 + c * 16 + quad * 4);
        }
        floatx4 acc[8];
        #pragma unroll
        for (int c = 0; c < 8; ++c) acc[c] = (floatx4){0.f, 0.f, 0.f, 0.f};
        #pragma unroll
        for (int kc = 0; kc < 4; ++kc)
            #pragma unroll
            for (int c = 0; c < 8; ++c)
                acc[c] = __builtin_amdgcn_mfma_f32_16x16x32_bf16(B[c][kc], Acur[kc], acc[c], 0, 0, 0);
        if (node < Nrows) {
            #pragma unroll
            for (int c = 0; c < 8; ++c) {
                int col0 = c * 16 + quad * 4;
                float4 bv = *(const float4*)(biasB + t * 128 + col0);
                float o0 = acc[c][0] + bv.x, o1 = acc[c][1] + bv.y;
                float o2 = acc[c][2] + bv.z, o3 = acc[c][3] + bv.w;
                if (SKIP) {
                    o0 = beta * o0 + omb * __uint_as_float(xo[c].x << 16);
                    o1 = beta * o1 + omb * __uint_as_float(xo[c].x & 0xffff0000u);
                    o2 = beta * o2 + omb * __uint_as_float(xo[c].y << 16);
                    o3 = beta * o3 + omb * __uint_as_float(xo[c].y & 0xffff0000u);
                }
                o0 = fmaxf(o0, 0.f); o1 = fmaxf(o1, 0.f);
                o2 = fmaxf(o2, 0.f); o3 = fmaxf(o3, 0.f);
                uint2 u;
                u.x = (unsigned)f2bf(o0) | ((unsigned)f2bf(o1) << 16);
                u.y = (unsigned)f2bf(o2) | ((unsigned)f2bf(o3) << 16);
                *(uint2*)(out + (size_t)node * 128 + col0) = u;
            }
        }
        #pragma unroll
        for (int kc = 0; kc < 4; ++kc) {
            if (AF32) {
                float af[8] = {Fnx[kc][0].x, Fnx[kc][0].y, Fnx[kc][0].z, Fnx[kc][0].w,
                               Fnx[kc][1].x, Fnx[kc][1].y, Fnx[kc][1].z, Fnx[kc][1].w};
                short8 a;
                #pragma unroll
                for (int i = 0; i < 8; ++i) a[i] = (short)f2bf(af[i]);
                Acur[kc] = a;
            } else if (GIN) {
                short8 a;
                #pragma unroll
                for (int i = 0; i < 8; ++i)
                    a[i] = (short)f2bf(gelu_fast(bf2f((unsigned short)Snx[kc][i])));
                Acur[kc] = a;
            } else {
                Acur[kc] = Snx[kc];
            }
        }
    }
}

// ---------------- output projection: one GEMM over all 96000 rows ----------
__global__ __launch_bounds__(256, 3) void gemm_out(
    const unsigned short* __restrict__ Abf,
    const unsigned short* __restrict__ Wt,     // [64][128] bf16^T
    const float* __restrict__ bias,
    float* __restrict__ out, int Nrows)
{
    const int wave = threadIdx.x >> 6, lane = threadIdx.x & 63;
    const int quad = lane >> 4, l16 = lane & 15;
    int p0 = blockIdx.x * 4, p1 = p0 + 4;

    short8 B[4][4];
    {
        const unsigned short* wb = Wt + (size_t)l16 * 128 + quad * 8;
        #pragma unroll
        for (int c = 0; c < 4; ++c)
            #pragma unroll
            for (int kc = 0; kc < 4; ++kc)
                B[c][kc] = *(const short8*)(wb + (size_t)c * 2048 + kc * 32);
    }
    float4 bv[4];
    #pragma unroll
    for (int c = 0; c < 4; ++c) bv[c] = *(const float4*)(bias + c * 16 + quad * 4);

    short8 Acur[4];
    {
        int m = p0 * 64 + wave * 16 + l16; if (m >= Nrows) m = Nrows - 1;
        const unsigned short* ap = Abf + (size_t)m * 128 + quad * 8;
        #pragma unroll
        for (int kc = 0; kc < 4; ++kc) Acur[kc] = *(const short8*)(ap + kc * 32);
    }
    for (int p = p0; p < p1; ++p) {
        short8 Anx[4];
        {
            int m = (p + 1) * 64 + wave * 16 + l16; if (m >= Nrows) m = Nrows - 1;
            const unsigned short* ap = Abf + (size_t)m * 128 + quad * 8;
            #pragma unroll
            for (int kc = 0; kc < 4; ++kc) Anx[kc] = *(const short8*)(ap + kc * 32);
        }
        floatx4 acc[4];
        #pragma unroll
        for (int c = 0; c < 4; ++c) acc[c] = (floatx4){0.f, 0.f, 0.f, 0.f};
        #pragma unroll
        for (int kc = 0; kc < 4; ++kc)
            #pragma unroll
            for (int c = 0; c < 4; ++c)
                acc[c] = __builtin_amdgcn_mfma_f32_16x16x32_bf16(B[c][kc], Acur[kc], acc[c], 0, 0, 0);
        int node = p * 64 + wave * 16 + l16;
        if (node < Nrows) {
            #pragma unroll
            for (int c = 0; c < 4; ++c) {
                float4 o;
                o.x = acc[c][0] + bv[c].x; o.y = acc[c][1] + bv[c].y;
                o.z = acc[c][2] + bv[c].z; o.w = acc[c][3] + bv[c].w;
                *(float4*)(out + (size_t)node * 64 + c * 16 + quad * 4) = o;
            }
        }
        #pragma unroll
        for (int kc = 0; kc < 4; ++kc) Acur[kc] = Anx[kc];
    }
}

// ------------------- fused weight prep (4 kernels -> 1) ---------------------
// blocks: [0,768) qpack / [768,1792) fold_rel / [1792,2944) w9 / [2944,3072) owt
__global__ __launch_bounds__(128) void prep_all(
    const float* __restrict__ qw, const float* __restrict__ qb,
    const float* __restrict__ kw, const float* __restrict__ kb,
    const float* __restrict__ vw, const float* __restrict__ vb,
    const float* __restrict__ a_rel, const float* __restrict__ m_rel,
    const float* __restrict__ lin_w, const float* __restrict__ aw,
    const float* __restrict__ ow,
    unsigned short* __restrict__ Wpack, float* __restrict__ bpack,
    unsigned short* __restrict__ lwt, unsigned short* __restrict__ awt,
    unsigned short* __restrict__ owt)
{
    const int pre[3] = {0, 49152, 131072};
    const int preB[3] = {0, 384, 1024};
    int b = blockIdx.x;
    if (b < 768) {
        int n = threadIdx.x;
        int k = b & 127, r = b >> 7, t = r % 3, l = r / 3;
        unsigned short* Wp = Wpack + (size_t)l * 180224 + pre[t];
        Wp[(size_t)n * 128 + k] = f2bf(qw[(size_t)(l * 3 + t) * 16384 + (size_t)k * 128 + n]);
        if (k == 0) bpack[l * 1408 + preB[t] + n] = qb[(l * 3 + t) * 128 + n];
    } else if (b < 1792) {
        const int SIv[4] = {0, 1, 1, 2};
        const int SLOT[4] = {0, 0, 1, 0};
        int bb = b - 768;
        int hf = threadIdx.x, h = hf >> 4, f = hf & 15;
        int c = bb & 127, et = (bb >> 7) & 3, l = bb >> 9;
        int si = SIv[et];
        const float* kwp  = kw + (size_t)(l * 3 + si) * 16384;
        const float* vwp  = vw + (size_t)(l * 3 + si) * 16384;
        const float* kbp  = kb + (size_t)(l * 3 + si) * 128;
        const float* vbp  = vb + (size_t)(l * 3 + si) * 128;
        const float* arel = a_rel + (size_t)(l * 4 + et) * 2048;
        const float* mrel = m_rel + (size_t)(l * 4 + et) * 2048;
        float sk = 0.f, sv = 0.f;
        #pragma unroll
        for (int d = 0; d < 16; ++d) {
            float ar = arel[(h * 16 + d) * 16 + f];
            float mr = mrel[(h * 16 + d) * 16 + f];
            sk = fmaf(kwp[c * 128 + h * 16 + d], ar, sk);
            sv = fmaf(vwp[c * 128 + h * 16 + d], mr, sv);
        }
        int rowoff = 128 + 256 * SLOT[et];
        unsigned short* Wp = Wpack + (size_t)l * 180224 + pre[si];
        Wp[(size_t)(rowoff + hf) * 128 + c]       = f2bf(sk);
        Wp[(size_t)(rowoff + 128 + hf) * 128 + c] = f2bf(sv);
        if (c == 0) {
            float bk = 0.f, bvv = 0.f;
            #pragma unroll
            for (int d = 0; d < 16; ++d) {
                bk  = fmaf(kbp[h * 16 + d], arel[(h * 16 + d) * 16 + f], bk);
                bvv = fmaf(vbp[h * 16 + d], mrel[(h * 16 + d) * 16 + f], bvv);
            }
            float* bp = bpack + l * 1408 + preB[si];
            bp[rowoff + hf]       = bk;
            bp[rowoff + 128 + hf] = bvv;
        }
    } else if (b < 2944) {
        int bb = b - 1792;
        int n = threadIdx.x, k = bb & 127, mi = bb >> 7;
        const float* w; unsigned short* wt; int m;
        if (mi < 3) { w = lin_w; wt = lwt; m = mi; }
        else        { w = aw;    wt = awt; m = mi - 3; }
        wt[(size_t)m * 16384 + (size_t)n * 128 + k] =
            f2bf(w[(size_t)m * 16384 + (size_t)k * 128 + n]);
    } else {
        int k = b - 2944, n = threadIdx.x;
        if (n < 64) owt[(size_t)n * 128 + k] = f2bf(ow[(size_t)k * 64 + n]);
    }
}

// ------------------------- CSR build (fused across edge types) --------------
__global__ __launch_bounds__(256) void hist_all(
    const int* __restrict__ d0, const int* __restrict__ d1,
    const int* __restrict__ d2, const int* __restrict__ d3,
    int* __restrict__ deg4)
{
    const int Ev[4] = {200000, 300000, 200000, 100000};
    int et = blockIdx.y;
    int e = blockIdx.x * 256 + threadIdx.x;
    if (e >= Ev[et]) return;
    const int* d = et == 0 ? d0 : et == 1 ? d1 : et == 2 ? d2 : d3;
    atomicAdd(&deg4[et * 60000 + d[e]], 1);
}

// computes per-tile rowptr prefix AND zeroes deg4 back for fill's cursors
__global__ __launch_bounds__(256) void scan_tile_all(
    int* __restrict__ deg4,
    int* __restrict__ r0, int* __restrict__ r1, int* __restrict__ r2, int* __restrict__ r3,
    int* __restrict__ tsum4)
{
    const int Ndv[4] = {60000, 60000, 6000, 30000};
    __shared__ int ls[256];
    int et = blockIdx.y;
    int n = Ndv[et];
    int* deg = deg4 + et * 60000;
    int* rowptr = et == 0 ? r0 : et == 1 ? r1 : et == 2 ? r2 : r3;
    int b = blockIdx.x, tid = threadIdx.x;
    int base = b * 1024 + tid * 4;
    int v0 = 0, v1 = 0, v2 = 0, v3 = 0;
    if (base + 3 < n) {
        int4 t = *(const int4*)(deg + base);
        v0 = t.x; v1 = t.y; v2 = t.z; v3 = t.w;
        *(int4*)(deg + base) = make_int4(0, 0, 0, 0);
    } else {
        if (base + 0 < n) { v0 = deg[base + 0]; deg[base + 0] = 0; }
        if (base + 1 < n) { v1 = deg[base + 1]; deg[base + 1] = 0; }
        if (base + 2 < n) { v2 = deg[base + 2]; deg[base + 2] = 0; }
        if (base + 3 < n) { v3 = deg[base + 3]; deg[base + 3] = 0; }
    }
    int s = v0 + v1 + v2 + v3;
    ls[tid] = s;
    __syncthreads();
    #pragma unroll
    for (int off = 1; off < 256; off <<= 1) {
        int t = (tid >= off) ? ls[tid - off] : 0;
        __syncthreads();
        ls[tid] += t;
        __syncthreads();
    }
    int run = ls[tid] - s;
    int o0 = run; run += v0;
    int o1 = run; run += v1;
    int o2 = run; run += v2;
    int o3 = run;
    if (base + 3 < n) {
        *(int4*)(rowptr + base) = make_int4(o0, o1, o2, o3);
    } else {
        if (base + 0 < n) rowptr[base + 0] = o0;
        if (base + 1 < n) rowptr[base + 1] = o1;
        if (base + 2 < n) rowptr[base + 2] = o2;
    }
    if (tid == 255) tsum4[et * 64 + b] = ls[255];
}

// adds tile-prefix (computed from raw per-tile sums in LDS) + writes total
__global__ __launch_bounds__(256) void scan_add_all(
    int* __restrict__ r0, int* __restrict__ r1, int* __restrict__ r2, int* __restrict__ r3,
    const int* __restrict__ tsum4)
{
    const int Ndv[4] = {60000, 60000, 6000, 30000};
    __shared__ int ts[64];
    int et = blockIdx.y;
    int n = Ndv[et];
    int* rowptr = et == 0 ? r0 : et == 1 ? r1 : et == 2 ? r2 : r3;
    int tid = threadIdx.x;
    if (tid < 64) ts[tid] = tsum4[et * 64 + tid];
    __syncthreads();
    int i = blockIdx.x * 256 + tid;
    int tile = i >> 10;
    int pre = 0;
    for (int j = 0; j < tile; ++j) pre += ts[j];
    if (i < n) rowptr[i] += pre;
    if (blockIdx.x == 0 && tid == 0) {
        int nt = (n + 1023) >> 10, tot = 0;
        for (int j = 0; j < nt; ++j) tot += ts[j];
        rowptr[n] = tot;
    }
}

__global__ __launch_bounds__(256) void fill_all(
    const int* __restrict__ s0, const int* __restrict__ d0,
    const int* __restrict__ s1, const int* __restrict__ d1,
    const int* __restrict__ s2, const int* __restrict__ d2,
    const int* __restrict__ s3, const int* __restrict__ d3,
    const int* __restrict__ r0, const int* __restrict__ r1,
    const int* __restrict__ r2, const int* __restrict__ r3,
    int* __restrict__ deg4,
    int* __restrict__ c0, int* __restrict__ c1, int* __restrict__ c2, int* __restrict__ c3)
{
    const int Ev[4] = {200000, 300000, 200000, 100000};
    int et = blockIdx.y;
    int e = blockIdx.x * 256 + threadIdx.x;
    if (e >= Ev[et]) return;
    const int* src = et == 0 ? s0 : et == 1 ? s1 : et == 2 ? s2 : s3;
    const int* dst = et == 0 ? d0 : et == 1 ? d1 : et == 2 ? d2 : d3;
    const int* rowptr = et == 0 ? r0 : et == 1 ? r1 : et == 2 ? r2 : r3;
    int* csr = et == 0 ? c0 : et == 1 ? c1 : et == 2 ? c2 : c3;
    int d = dst[e];
    int pos = atomicAdd(&deg4[et * 60000 + d], 1);
    csr[rowptr[d] + pos] = src[e];
}

// --------------- merged gather-side attention (all 4 edge types) ------------
// Depth-2 paired pipeline; defer-max (THR=8, exact).
__device__ __forceinline__ void attn_edge(
    uint4 k0, uint4 k1, uint4 v0, uint4 v1,
    const float* qf, float ph, float& m, float& l, float* o)
{
    float kf[16];
    up8(k0, kf); up8(k1, kf + 8);
    float a = 0.f;
    #pragma unroll
    for (int i = 0; i < 16; ++i) a = fmaf(qf[i], kf[i], a);
    a *= ph;
    float d = a - m;
    if (d > 8.f) {
        float sc = __expf(-d);
        l *= sc;
        #pragma unroll
        for (int i = 0; i < 16; ++i) o[i] *= sc;
        m = a; d = 0.f;
    }
    float w = __expf(d);
    l += w;
    float vf[16];
    up8(v0, vf); up8(v1, vf + 8);
    #pragma unroll
    for (int i = 0; i < 16; ++i) o[i] = fmaf(w, vf[i], o[i]);
}

__device__ __forceinline__ void attn_run(
    const int* __restrict__ csr, int beg, int end,
    const unsigned short* __restrict__ kbase, int ld,
    const float* qf, float ph, float& m, float& l, float* o)
{
    int n = end - beg;
    if (n <= 0) return;
    const uint4* pA = (const uint4*)(kbase + (size_t)csr[beg] * ld);
    uint4 A0 = pA[0], A1 = pA[1], A2 = pA[16], A3 = pA[17];
    uint4 B0 = A0, B1 = A1, B2 = A2, B3 = A3;
    if (n > 1) {
        const uint4* pB = (const uint4*)(kbase + (size_t)csr[beg + 1] * ld);
        B0 = pB[0]; B1 = pB[1]; B2 = pB[16]; B3 = pB[17];
    }
    int j = beg;
    for (; j + 3 < end; j += 2) {
        const uint4* pC = (const uint4*)(kbase + (size_t)csr[j + 2] * ld);
        const uint4* pD = (const uint4*)(kbase + (size_t)csr[j + 3] * ld);
        uint4 C0 = pC[0], C1 = pC[1], C2 = pC[16], C3 = pC[17];
        uint4 D0 = pD[0], D1 = pD[1], D2 = pD[16], D3 = pD[17];
        float kf0[16], kf1[16];
        up8(A0, kf0); up8(A1, kf0 + 8);
        up8(B0, kf1); up8(B1, kf1 + 8);
        float a0 = 0.f, a1 = 0.f;
        #pragma unroll
        for (int i = 0; i < 16; ++i) {
            a0 = fmaf(qf[i], kf0[i], a0);
            a1 = fmaf(qf[i], kf1[i], a1);
        }
        a0 *= ph; a1 *= ph;
        float hi = fmaxf(a0, a1);
        float d = hi - m;
        if (d > 8.f) {
            float sc = __expf(-d);
            l *= sc;
            #pragma unroll
            for (int i = 0; i < 16; ++i) o[i] *= sc;
            m = hi;
        }
        float w0 = __expf(a0 - m), w1 = __expf(a1 - m);
        l += w0 + w1;
        float vf0[16], vf1[16];
        up8(A2, vf0); up8(A3, vf0 + 8);
        up8(B2, vf1); up8(B3, vf1 + 8);
        #pragma unroll
        for (int i = 0; i < 16; ++i)
            o[i] = fmaf(w1, vf1[i], fmaf(w0, vf0[i], o[i]));
        A0 = C0; A1 = C1; A2 = C2; A3 = C3;
        B0 = D0; B1 = D1; B2 = D2; B3 = D3;
    }
    int rem = end - j;                      // 1..3
    attn_edge(A0, A1, A2, A3, qf, ph, m, l, o);
    if (rem >= 2) attn_edge(B0, B1, B2, B3, qf, ph, m, l, o);
    if (rem == 3) {
        const uint4* pC = (const uint4*)(kbase + (size_t)csr[j + 2] * ld);
        attn_edge(pC[0], pC[1], pC[16], pC[17], qf, ph, m, l, o);
    }
}

// merge partial online-softmax state across lanes (xor st)
__device__ __forceinline__ void merge_sm(float& m, float& l, float* o, int st)
{
    float mp = __shfl_xor(m, st);
    float lp = __shfl_xor(l, st);
    float mn = fmaxf(m, mp);
    float sc  = (l  > 0.f) ? __expf(m  - mn) : 0.f;
    float scp = (lp > 0.f) ? __expf(mp - mn) : 0.f;
    l = l * sc + lp * scp;
    #pragma unroll
    for (int i = 0; i < 16; ++i) {
        float op = __shfl_xor(o[i], st);
        o[i] = o[i] * sc + op * scp;
    }
    m = mn;
}

// grid: [0,3750) road (et0 & et1 on parallel lanes, 16 lanes/node) /
//       [3750,4500) region (et2, 4-way split) / [4500,5438) poi (et3 serial)
__global__ __launch_bounds__(256) void agg_all(
    const int* __restrict__ rp0, const int* __restrict__ cs0,
    const int* __restrict__ rp1, const int* __restrict__ cs1,
    const int* __restrict__ rp2, const int* __restrict__ cs2,
    const int* __restrict__ rp3, const int* __restrict__ cs3,
    const unsigned short* __restrict__ P0, const unsigned short* __restrict__ P1,
    const unsigned short* __restrict__ P2,
    const float* __restrict__ prl,      // p_rel + l*32
    unsigned short* __restrict__ num)
{
    int gb = blockIdx.x, tid = threadIdx.x;
    float qf[16], o[16], r[16];
    if (gb < 3750) {
        // ---- road: lane = (node, h, half); half0 runs et0, half1 runs et1,
        //      FULL runs in parallel; combine normalized partials via xor-8.
        int t = gb * 256 + tid;            // < 960000 exactly
        int node = t >> 4, h = t & 7, half = (t >> 3) & 1;
        const uint4* qp = (const uint4*)(P1 + (size_t)node * 640 + h * 16);
        up8(qp[0], qf); up8(qp[1], qf + 8);
        const int* csr = half ? cs1 : cs0;
        const int* rp  = half ? rp1 : rp0;
        const unsigned short* kb = half ? (P1 + 128 + h * 16) : (P0 + 128 + h * 16);
        int ld = half ? 640 : 384;
        float ph = prl[(half ? 8 : 0) + h] * 0.25f;
        float m = -INFINITY, l = 0.f;
        #pragma unroll
        for (int i = 0; i < 16; ++i) o[i] = 0.f;
        attn_run(csr, rp[node], rp[node + 1], kb, ld, qf, ph, m, l, o);
        float inv = 1.f / (l + 1e-16f);
        #pragma unroll
        for (int i = 0; i < 16; ++i) r[i] = inv * o[i];
        #pragma unroll
        for (int i = 0; i < 16; ++i) r[i] += __shfl_xor(r[i], 8);
        if (half) return;
        uint4* np = (uint4*)(num + (size_t)(30000 + node) * 128 + h * 16);
        np[0] = pk8(r); np[1] = pk8(r + 8);
    } else if (gb < 4500) {
        // ---- region: et2 (road src), 4-way edge split + shuffle merge ----
        int t = (gb - 3750) * 256 + tid;   // < 192000 exactly
        int node = t >> 5, h = t & 7, sub = (t >> 3) & 3;
        int beg0 = rp2[node], end0 = rp2[node + 1];
        int n = end0 - beg0;
        int beg = beg0 + ((n * sub) >> 2);
        int end = beg0 + ((n * (sub + 1)) >> 2);
        const uint4* qp = (const uint4*)(P2 + (size_t)node * 384 + h * 16);
        up8(qp[0], qf); up8(qp[1], qf + 8);
        float m = -INFINITY, l = 0.f;
        #pragma unroll
        for (int i = 0; i < 16; ++i) o[i] = 0.f;
        attn_run(cs2, beg, end, P1 + 384 + h * 16, 640,
                 qf, prl[16 + h] * 0.25f, m, l, o);
        merge_sm(m, l, o, 8);
        merge_sm(m, l, o, 16);
        if (sub) return;
        float inv = 1.f / (l + 1e-16f);
        #pragma unroll
        for (int i = 0; i < 16; ++i) r[i] = inv * o[i];
        uint4* np = (uint4*)(num + (size_t)(90000 + node) * 128 + h * 16);
        np[0] = pk8(r); np[1] = pk8(r + 8);
    } else {
        // ---- poi: et3 (region src), serial run ----
        int t = (gb - 4500) * 256 + tid;
        if (t >= 240000) return;
        int node = t >> 3, h = t & 7;
        const uint4* qp = (const uint4*)(P0 + (size_t)node * 384 + h * 16);
        up8(qp[0], qf); up8(qp[1], qf + 8);
        float m = -INFINITY, l = 0.f;
        #pragma unroll
        for (int i = 0; i < 16; ++i) o[i] = 0.f;
        attn_run(cs3, rp3[node], rp3[node + 1], P2 + 128 + h * 16, 384,
                 qf, prl[24 + h] * 0.25f, m, l, o);
        float inv = 1.f / (l + 1e-16f);
        #pragma unroll
        for (int i = 0; i < 16; ++i) r[i] = inv * o[i];
        uint4* np = (uint4*)(num + (size_t)node * 128 + h * 16);
        np[0] = pk8(r); np[1] = pk8(r + 8);
    }
}

extern "C" void kernel_launch(void* const* d_in, const int* in_sizes, int n_in,
                              void* d_out, int out_size, void* d_ws, size_t ws_size,
                              hipStream_t stream)
{
    (void)in_sizes; (void)n_in; (void)out_size; (void)ws_size;

    const float* xin[3] = {(const float*)d_in[0], (const float*)d_in[1], (const float*)d_in[2]};
    const int* esrc[4] = {(const int*)d_in[3], (const int*)d_in[5], (const int*)d_in[7], (const int*)d_in[9]};
    const int* edst[4] = {(const int*)d_in[4], (const int*)d_in[6], (const int*)d_in[8], (const int*)d_in[10]};
    const float* lin_w = (const float*)d_in[11];
    const float* lin_b = (const float*)d_in[12];
    const float* kw = (const float*)d_in[13];
    const float* qw = (const float*)d_in[14];
    const float* vw = (const float*)d_in[15];
    const float* aw = (const float*)d_in[16];
    const float* kb = (const float*)d_in[17];
    const float* qb = (const float*)d_in[18];
    const float* vb = (const float*)d_in[19];
    const float* ab = (const float*)d_in[20];
    const float* a_rel = (const float*)d_in[21];
    const float* m_rel = (const float*)d_in[22];
    const float* p_rel = (const float*)d_in[23];
    const float* skip  = (const float*)d_in[24];
    const float* out_w = (const float*)d_in[25];
    const float* out_b = (const float*)d_in[26];

    // workspace (float-index units; ~39.9M floats = 160 MB)
    float* ws = (float*)d_ws;
    unsigned short* num   = (unsigned short*)ws;                // 12,288,000 h
    unsigned short* xs_bf = (unsigned short*)(ws + 6144000);    // 12,288,000 h
    unsigned short* proj  = (unsigned short*)(ws + 12288000);   // 52,224,000 h
    unsigned short* Wpack = (unsigned short*)(ws + 38400000);   // 360,448 h
    unsigned short* lwt   = (unsigned short*)(ws + 38580224);   // 49,152 h
    unsigned short* awt   = (unsigned short*)(ws + 38604800);   // 98,304 h
    unsigned short* owt   = (unsigned short*)(ws + 38653952);   // 8,192 h
    float*          bpack = ws + 38658048;                      // 2,816 f
    int*            deg4  = (int*)(ws + 38660864);              // 240,000
    int*            tsum4 = (int*)(ws + 38900864);              // 256
    int* rp[4];
    rp[0] = (int*)(ws + 38901120);                              // 60,008
    rp[1] = (int*)(ws + 38961128);
    rp[2] = (int*)(ws + 39021136);                              // 6,008
    rp[3] = (int*)(ws + 39027144);                              // 30,008
    int* cs[4];
    cs[0] = (int*)(ws + 39057152);                              // 200,000
    cs[1] = (int*)(ws + 39257152);                              // 300,000
    cs[2] = (int*)(ws + 39557152);                              // 200,000
    cs[3] = (int*)(ws + 39757152);                              // 100,000

    unsigned short* P[3];
    P[0] = proj;
    P[1] = proj + (size_t)30000 * 384;
    P[2] = proj + (size_t)30000 * 384 + (size_t)60000 * 640;

    dim3 blk(256);

    // ---- CSR build, fused across edge types (4 kernels + 1 memset) ----
    hipMemsetAsync(deg4, 0, 960000, stream);
    hist_all<<<dim3(1172, 4), blk, 0, stream>>>(edst[0], edst[1], edst[2], edst[3], deg4);
    scan_tile_all<<<dim3(59, 4), blk, 0, stream>>>(deg4, rp[0], rp[1], rp[2], rp[3], tsum4);
    scan_add_all<<<dim3(235, 4), blk, 0, stream>>>(rp[0], rp[1], rp[2], rp[3], tsum4);
    fill_all<<<dim3(1172, 4), blk, 0, stream>>>(
        esrc[0], edst[0], esrc[1], edst[1], esrc[2], edst[2], esrc[3], edst[3],
        rp[0], rp[1], rp[2], rp[3], deg4, cs[0], cs[1], cs[2], cs[3]);

    // ---- weight prep (fused) ----
    prep_all<<<dim3(3072), dim3(128), 0, stream>>>(
        qw, qb, kw, kb, vw, vb, a_rel, m_rel, lin_w, aw, out_w,
        Wpack, bpack, lwt, awt, owt);

    // ---- input linear + relu -> xs_bf (fused across types) ----
    gemm_node<true, false, false><<<dim3(377), blk, 0, stream>>>(
        xin[0], xin[1], xin[2], lwt, lin_b, nullptr, nullptr, xs_bf);

    for (int l = 0; l < 2; ++l) {
        // packed projection per node type: [q | ka|mv ...], one fused launch
        gemm_proj_all<<<dim3(803), blk, 0, stream>>>(
            xs_bf, Wpack + (size_t)l * 180224, bpack + l * 1408, proj);

        // merged aggregation: all 4 edge types in one launch
        agg_all<<<dim3(5438), blk, 0, stream>>>(
            rp[0], cs[0], rp[1], cs[1], rp[2], cs[2], rp[3], cs[3],
            P[0], P[1], P[2], p_rel + (size_t)l * 32, num);

        // node update (fused across types)
        gemm_node<false, true, true><<<dim3(377), blk, 0, stream>>>(
            num, num + (size_t)30000 * 128, num + (size_t)90000 * 128,
            awt + (size_t)l * 3 * 16384, ab + (size_t)l * 3 * 128,
            xs_bf, skip + l * 3, xs_bf);
    }

    // ---- output projection: single GEMM over all 96000 rows ----
    gemm_out<<<dim3(375), blk, 0, stream>>>(
        xs_bf, owt, out_b, (float*)d_out, 96000);
}

// Round 10
// 555.218 us; speedup vs baseline: 1.0566x; 1.0222x over previous
//
#include <hip/hip_runtime.h>
#include <cstddef>
#include <cstdint>

// ---------------------------------------------------------------------------
// HGT forward for MI355X. C=128, H=8, D=16, OUT=64, L=2
//   NN = {30000, 60000, 6000}, NE = {200000, 300000, 200000, 100000}
//   ETS = {(0,1),(1,1),(1,2),(2,0)}
// Round-19 changes:
//  * Dispatch fusion of INDEPENDENT kernels (block-range split, zero
//    numeric change): hist_all+prep_all -> hist_prep (6224 blocks);
//    fill_all+input-linear gemm_node -> fill_nodein (5065 blocks).
//    14 -> 12 dispatches; fill (~15us) overlaps under node-in GEMM,
//    prep under hist. r6->r7 measured ~4us per removed dispatch.
//  * All kernel bodies identical to r9 (567.5us state).
// ---------------------------------------------------------------------------

typedef __attribute__((ext_vector_type(8))) short short8;   // 8 x bf16
typedef __attribute__((ext_vector_type(4))) float floatx4;

__device__ __forceinline__ float gelu_fast(float x) {
    float u = 1.5957691216057308f * x * (1.0f + 0.044715f * x * x);
    return x / (1.0f + __expf(-u));
}

__device__ __forceinline__ unsigned short f2bf(float f) {   // RNE fp32->bf16
    unsigned u = __float_as_uint(f);
    u += 0x7fffu + ((u >> 16) & 1);
    return (unsigned short)(u >> 16);
}

__device__ __forceinline__ float bf2f(unsigned short h) {
    return __uint_as_float((unsigned)h << 16);
}

__device__ __forceinline__ void up8(uint4 u, float* f) {    // 8 bf16 -> 8 fp32
    f[0] = __uint_as_float(u.x << 16); f[1] = __uint_as_float(u.x & 0xffff0000u);
    f[2] = __uint_as_float(u.y << 16); f[3] = __uint_as_float(u.y & 0xffff0000u);
    f[4] = __uint_as_float(u.z << 16); f[5] = __uint_as_float(u.z & 0xffff0000u);
    f[6] = __uint_as_float(u.w << 16); f[7] = __uint_as_float(u.w & 0xffff0000u);
}

__device__ __forceinline__ uint4 pk8(const float* f) {      // 8 fp32 -> 8 bf16
    uint4 u;
    u.x = (unsigned)f2bf(f[0]) | ((unsigned)f2bf(f[1]) << 16);
    u.y = (unsigned)f2bf(f[2]) | ((unsigned)f2bf(f[3]) << 16);
    u.z = (unsigned)f2bf(f[4]) | ((unsigned)f2bf(f[5]) << 16);
    u.w = (unsigned)f2bf(f[6]) | ((unsigned)f2bf(f[7]) << 16);
    return u;
}

// ---------------- W-resident streaming MFMA GEMM (packed proj) -------------
// cp-major (r7 config): road [0,590)=5cp x 118rb / poi [590,767)=3cp x 59 /
// region [767,803)=3cp x 12. 8 panels (512 rows) per block.
__global__ __launch_bounds__(256, 2) void gemm_proj_all(
    const unsigned short* __restrict__ xs_bf,
    const unsigned short* __restrict__ Wl,     // Wpack + l*180224
    const float* __restrict__ bl,              // bpack + l*1408
    unsigned short* __restrict__ proj)
{
    const int    NN_[3]  = {30000, 60000, 6000};
    const int    NPAN[3] = {469, 938, 94};
    const int    OFFr[3] = {0, 30000, 90000};
    const int    WOFF[3] = {0, 49152, 131072};
    const int    BOFF[3] = {0, 384, 1024};
    const size_t POFF[3] = {0, 11520000u, 49920000u};
    const int    LDO[3]  = {384, 640, 384};

    int b = blockIdx.x, t, cp, rb;
    if (b < 590)      { t = 1; cp = b / 118; rb = b - cp * 118; }
    else if (b < 767) { int lb = b - 590; t = 0; cp = lb / 59; rb = lb - cp * 59; }
    else              { int lb = b - 767; t = 2; cp = lb / 12; rb = lb - cp * 12; }
    int p0 = rb * 8, p1 = p0 + 8;
    if (p1 > NPAN[t]) p1 = NPAN[t];

    const unsigned short* Abf = xs_bf + (size_t)OFFr[t] * 128;
    const unsigned short* Wt  = Wl + WOFF[t];
    const float* bias = bl + BOFF[t] + cp * 128;
    unsigned short* outbf = proj + POFF[t];
    const int ldo = LDO[t], Nrows = NN_[t];

    const int wave = threadIdx.x >> 6, lane = threadIdx.x & 63;
    const int quad = lane >> 4, l16 = lane & 15;

    short8 B[2][4][4];
    {
        const unsigned short* wb = Wt + (size_t)(cp * 128 + l16) * 128 + quad * 8;
        #pragma unroll
        for (int T = 0; T < 2; ++T)
            #pragma unroll
            for (int c = 0; c < 4; ++c)
                #pragma unroll
                for (int kc = 0; kc < 4; ++kc)
                    B[T][c][kc] = *(const short8*)(wb + (size_t)(T * 64 + c * 16) * 128 + kc * 32);
    }
    float4 bv[2][4];
    #pragma unroll
    for (int T = 0; T < 2; ++T)
        #pragma unroll
        for (int c = 0; c < 4; ++c)
            bv[T][c] = *(const float4*)(bias + T * 64 + c * 16 + quad * 4);

    short8 Acur[4];
    {
        int m = p0 * 64 + wave * 16 + l16; if (m >= Nrows) m = Nrows - 1;
        const unsigned short* ap = Abf + (size_t)m * 128 + quad * 8;
        #pragma unroll
        for (int kc = 0; kc < 4; ++kc) Acur[kc] = *(const short8*)(ap + kc * 32);
    }
    for (int p = p0; p < p1; ++p) {
        short8 Anx[4];
        {
            int m = (p + 1) * 64 + wave * 16 + l16; if (m >= Nrows) m = Nrows - 1;
            const unsigned short* ap = Abf + (size_t)m * 128 + quad * 8;
            #pragma unroll
            for (int kc = 0; kc < 4; ++kc) Anx[kc] = *(const short8*)(ap + kc * 32);
        }
        floatx4 acc[2][4];
        #pragma unroll
        for (int T = 0; T < 2; ++T)
            #pragma unroll
            for (int c = 0; c < 4; ++c) acc[T][c] = (floatx4){0.f, 0.f, 0.f, 0.f};
        #pragma unroll
        for (int kc = 0; kc < 4; ++kc)
            #pragma unroll
            for (int T = 0; T < 2; ++T)
                #pragma unroll
                for (int c = 0; c < 4; ++c)
                    acc[T][c] = __builtin_amdgcn_mfma_f32_16x16x32_bf16(B[T][c][kc], Acur[kc], acc[T][c], 0, 0, 0);
        int node = p * 64 + wave * 16 + l16;
        if (node < Nrows) {
            unsigned short* op = outbf + (size_t)node * ldo + cp * 128 + quad * 4;
            #pragma unroll
            for (int T = 0; T < 2; ++T)
                #pragma unroll
                for (int c = 0; c < 4; ++c) {
                    uint2 u;
                    u.x = (unsigned)f2bf(acc[T][c][0] + bv[T][c].x) |
                          ((unsigned)f2bf(acc[T][c][1] + bv[T][c].y) << 16);
                    u.y = (unsigned)f2bf(acc[T][c][2] + bv[T][c].z) |
                          ((unsigned)f2bf(acc[T][c][3] + bv[T][c].w) << 16);
                    *(uint2*)(op + T * 64 + c * 16) = u;
                }
        }
        #pragma unroll
        for (int kc = 0; kc < 4; ++kc) Acur[kc] = Anx[kc];
    }
}

// ---------------- fused-by-type node GEMM (layer update) -------------------
// 4 panels (256 rows) per block: poi [0,118) / road [118,353) / region
// [353,377).
template<bool AF32, bool GIN, bool SKIP>
__global__ __launch_bounds__(256, 2) void gemm_node(
    const void* __restrict__ a0v, const void* __restrict__ a1v, const void* __restrict__ a2v,
    const unsigned short* __restrict__ WtB, const float* __restrict__ biasB,
    const unsigned short* __restrict__ xoldB, const float* __restrict__ skipB,
    unsigned short* __restrict__ outB)
{
    const int TN[3]   = {30000, 60000, 6000};
    const int NPAN[3] = {469, 938, 94};
    const int TOFF[3] = {0, 30000, 90000};
    int b = blockIdx.x, t, rb;
    if (b < 118)      { t = 0; rb = b; }
    else if (b < 353) { t = 1; rb = b - 118; }
    else              { t = 2; rb = b - 353; }
    int p0 = rb * 4, p1 = p0 + 4;
    if (p1 > NPAN[t]) p1 = NPAN[t];
    int Nrows = TN[t];
    const void* av = (t == 0) ? a0v : (t == 1) ? a1v : a2v;
    const unsigned short* xold = xoldB + (size_t)TOFF[t] * 128;
    unsigned short* out = outB + (size_t)TOFF[t] * 128;

    const int wave = threadIdx.x >> 6, lane = threadIdx.x & 63;
    const int quad = lane >> 4, l16 = lane & 15;

    short8 B[8][4];
    {
        const unsigned short* wb = WtB + (size_t)t * 16384 + (size_t)l16 * 128 + quad * 8;
        #pragma unroll
        for (int c = 0; c < 8; ++c)
            #pragma unroll
            for (int kc = 0; kc < 4; ++kc)
                B[c][kc] = *(const short8*)(wb + (size_t)c * 2048 + kc * 32);
    }
    float beta = 0.f, omb = 0.f;
    if (SKIP) { beta = 1.0f / (1.0f + __expf(-skipB[t])); omb = 1.0f - beta; }

    short8 Acur[4];
    {
        int m = p0 * 64 + wave * 16 + l16; if (m >= Nrows) m = Nrows - 1;
        size_t base = (size_t)m * 128 + quad * 8;
        #pragma unroll
        for (int kc = 0; kc < 4; ++kc) {
            if (AF32) {
                const float* ap = (const float*)av + base;
                float4 f0 = *(const float4*)(ap + kc * 32);
                float4 f1 = *(const float4*)(ap + kc * 32 + 4);
                float af[8] = {f0.x, f0.y, f0.z, f0.w, f1.x, f1.y, f1.z, f1.w};
                short8 a;
                #pragma unroll
                for (int i = 0; i < 8; ++i) a[i] = (short)f2bf(af[i]);
                Acur[kc] = a;
            } else if (GIN) {
                const unsigned short* ap = (const unsigned short*)av + base;
                short8 a8 = *(const short8*)(ap + kc * 32);
                short8 a;
                #pragma unroll
                for (int i = 0; i < 8; ++i)
                    a[i] = (short)f2bf(gelu_fast(bf2f((unsigned short)a8[i])));
                Acur[kc] = a;
            } else {
                const unsigned short* ap = (const unsigned short*)av + base;
                Acur[kc] = *(const short8*)(ap + kc * 32);
            }
        }
    }
    for (int p = p0; p < p1; ++p) {
        float4 Fnx[4][2];
        short8 Snx[4];
        {
            int m = (p + 1) * 64 + wave * 16 + l16; if (m >= Nrows) m = Nrows - 1;
            size_t base = (size_t)m * 128 + quad * 8;
            #pragma unroll
            for (int kc = 0; kc < 4; ++kc) {
                if (AF32) {
                    const float* ap = (const float*)av + base;
                    Fnx[kc][0] = *(const float4*)(ap + kc * 32);
                    Fnx[kc][1] = *(const float4*)(ap + kc * 32 + 4);
                } else {
                    const unsigned short* ap = (const unsigned short*)av + base;
                    Snx[kc] = *(const short8*)(ap + kc * 32);
                }
            }
        }
        int node = p * 64 + wave * 16 + l16;
        int ncl = (node < Nrows) ? node : (Nrows - 1);
        uint2 xo[8];
        if (SKIP) {
            #pragma unroll
            for (int c = 0; c < 8; ++c)
                xo[c] = *(const uint2*)(xold + (size_t)ncl * 128 + c * 16 + quad * 4);
        }
        floatx4 acc[8];
        #pragma unroll
        for (int c = 0; c < 8; ++c) acc[c] = (floatx4){0.f, 0.f, 0.f, 0.f};
        #pragma unroll
        for (int kc = 0; kc < 4; ++kc)
            #pragma unroll
            for (int c = 0; c < 8; ++c)
                acc[c] = __builtin_amdgcn_mfma_f32_16x16x32_bf16(B[c][kc], Acur[kc], acc[c], 0, 0, 0);
        if (node < Nrows) {
            #pragma unroll
            for (int c = 0; c < 8; ++c) {
                int col0 = c * 16 + quad * 4;
                float4 bv = *(const float4*)(biasB + t * 128 + col0);
                float o0 = acc[c][0] + bv.x, o1 = acc[c][1] + bv.y;
                float o2 = acc[c][2] + bv.z, o3 = acc[c][3] + bv.w;
                if (SKIP) {
                    o0 = beta * o0 + omb * __uint_as_float(xo[c].x << 16);
                    o1 = beta * o1 + omb * __uint_as_float(xo[c].x & 0xffff0000u);
                    o2 = beta * o2 + omb * __uint_as_float(xo[c].y << 16);
                    o3 = beta * o3 + omb * __uint_as_float(xo[c].y & 0xffff0000u);
                }
                o0 = fmaxf(o0, 0.f); o1 = fmaxf(o1, 0.f);
                o2 = fmaxf(o2, 0.f); o3 = fmaxf(o3, 0.f);
                uint2 u;
                u.x = (unsigned)f2bf(o0) | ((unsigned)f2bf(o1) << 16);
                u.y = (unsigned)f2bf(o2) | ((unsigned)f2bf(o3) << 16);
                *(uint2*)(out + (size_t)node * 128 + col0) = u;
            }
        }
        #pragma unroll
        for (int kc = 0; kc < 4; ++kc) {
            if (AF32) {
                float af[8] = {Fnx[kc][0].x, Fnx[kc][0].y, Fnx[kc][0].z, Fnx[kc][0].w,
                               Fnx[kc][1].x, Fnx[kc][1].y, Fnx[kc][1].z, Fnx[kc][1].w};
                short8 a;
                #pragma unroll
                for (int i = 0; i < 8; ++i) a[i] = (short)f2bf(af[i]);
                Acur[kc] = a;
            } else if (GIN) {
                short8 a;
                #pragma unroll
                for (int i = 0; i < 8; ++i)
                    a[i] = (short)f2bf(gelu_fast(bf2f((unsigned short)Snx[kc][i])));
                Acur[kc] = a;
            } else {
                Acur[kc] = Snx[kc];
            }
        }
    }
}

// ---------------- output projection: one GEMM over all 96000 rows ----------
__global__ __launch_bounds__(256, 3) void gemm_out(
    const unsigned short* __restrict__ Abf,
    const unsigned short* __restrict__ Wt,     // [64][128] bf16^T
    const float* __restrict__ bias,
    float* __restrict__ out, int Nrows)
{
    const int wave = threadIdx.x >> 6, lane = threadIdx.x & 63;
    const int quad = lane >> 4, l16 = lane & 15;
    int p0 = blockIdx.x * 4, p1 = p0 + 4;

    short8 B[4][4];
    {
        const unsigned short* wb = Wt + (size_t)l16 * 128 + quad * 8;
        #pragma unroll
        for (int c = 0; c < 4; ++c)
            #pragma unroll
            for (int kc = 0; kc < 4; ++kc)
                B[c][kc] = *(const short8*)(wb + (size_t)c * 2048 + kc * 32);
    }
    float4 bv[4];
    #pragma unroll
    for (int c = 0; c < 4; ++c) bv[c] = *(const float4*)(bias + c * 16 + quad * 4);

    short8 Acur[4];
    {
        int m = p0 * 64 + wave * 16 + l16; if (m >= Nrows) m = Nrows - 1;
        const unsigned short* ap = Abf + (size_t)m * 128 + quad * 8;
        #pragma unroll
        for (int kc = 0; kc < 4; ++kc) Acur[kc] = *(const short8*)(ap + kc * 32);
    }
    for (int p = p0; p < p1; ++p) {
        short8 Anx[4];
        {
            int m = (p + 1) * 64 + wave * 16 + l16; if (m >= Nrows) m = Nrows - 1;
            const unsigned short* ap = Abf + (size_t)m * 128 + quad * 8;
            #pragma unroll
            for (int kc = 0; kc < 4; ++kc) Anx[kc] = *(const short8*)(ap + kc * 32);
        }
        floatx4 acc[4];
        #pragma unroll
        for (int c = 0; c < 4; ++c) acc[c] = (floatx4){0.f, 0.f, 0.f, 0.f};
        #pragma unroll
        for (int kc = 0; kc < 4; ++kc)
            #pragma unroll
            for (int c = 0; c < 4; ++c)
                acc[c] = __builtin_amdgcn_mfma_f32_16x16x32_bf16(B[c][kc], Acur[kc], acc[c], 0, 0, 0);
        int node = p * 64 + wave * 16 + l16;
        if (node < Nrows) {
            #pragma unroll
            for (int c = 0; c < 4; ++c) {
                float4 o;
                o.x = acc[c][0] + bv[c].x; o.y = acc[c][1] + bv[c].y;
                o.z = acc[c][2] + bv[c].z; o.w = acc[c][3] + bv[c].w;
                *(float4*)(out + (size_t)node * 64 + c * 16 + quad * 4) = o;
            }
        }
        #pragma unroll
        for (int kc = 0; kc < 4; ++kc) Acur[kc] = Anx[kc];
    }
}

// ------------- merged: edge histogram (4 ets) + weight prep ----------------
// blocks [0,4688): hist (et = b/1172); [4688,6224): prep (2x128-thread units
// per 256-thread block; 3072 units total: [0,768) qpack / [768,1792)
// fold_rel / [1792,2944) w9 / [2944,3072) owt).
__global__ __launch_bounds__(256) void hist_prep(
    const int* __restrict__ d0, const int* __restrict__ d1,
    const int* __restrict__ d2, const int* __restrict__ d3,
    int* __restrict__ deg4,
    const float* __restrict__ qw, const float* __restrict__ qb,
    const float* __restrict__ kw, const float* __restrict__ kb,
    const float* __restrict__ vw, const float* __restrict__ vb,
    const float* __restrict__ a_rel, const float* __restrict__ m_rel,
    const float* __restrict__ lin_w, const float* __restrict__ aw,
    const float* __restrict__ ow,
    unsigned short* __restrict__ Wpack, float* __restrict__ bpack,
    unsigned short* __restrict__ lwt, unsigned short* __restrict__ awt,
    unsigned short* __restrict__ owt)
{
    int b = blockIdx.x;
    if (b < 4688) {
        const int Ev[4] = {200000, 300000, 200000, 100000};
        int et = b / 1172, bx = b - et * 1172;
        int e = bx * 256 + threadIdx.x;
        if (e >= Ev[et]) return;
        const int* d = et == 0 ? d0 : et == 1 ? d1 : et == 2 ? d2 : d3;
        atomicAdd(&deg4[et * 60000 + d[e]], 1);
        return;
    }
    const int pre[3] = {0, 49152, 131072};
    const int preB[3] = {0, 384, 1024};
    int unit = (b - 4688) * 2 + (threadIdx.x >> 7);
    int tid = threadIdx.x & 127;
    if (unit < 768) {
        int n = tid;
        int k = unit & 127, r = unit >> 7, t = r % 3, l = r / 3;
        unsigned short* Wp = Wpack + (size_t)l * 180224 + pre[t];
        Wp[(size_t)n * 128 + k] = f2bf(qw[(size_t)(l * 3 + t) * 16384 + (size_t)k * 128 + n]);
        if (k == 0) bpack[l * 1408 + preB[t] + n] = qb[(l * 3 + t) * 128 + n];
    } else if (unit < 1792) {
        const int SIv[4] = {0, 1, 1, 2};
        const int SLOT[4] = {0, 0, 1, 0};
        int bb = unit - 768;
        int hf = tid, h = hf >> 4, f = hf & 15;
        int c = bb & 127, et = (bb >> 7) & 3, l = bb >> 9;
        int si = SIv[et];
        const float* kwp  = kw + (size_t)(l * 3 + si) * 16384;
        const float* vwp  = vw + (size_t)(l * 3 + si) * 16384;
        const float* kbp  = kb + (size_t)(l * 3 + si) * 128;
        const float* vbp  = vb + (size_t)(l * 3 + si) * 128;
        const float* arel = a_rel + (size_t)(l * 4 + et) * 2048;
        const float* mrel = m_rel + (size_t)(l * 4 + et) * 2048;
        float sk = 0.f, sv = 0.f;
        #pragma unroll
        for (int d = 0; d < 16; ++d) {
            float ar = arel[(h * 16 + d) * 16 + f];
            float mr = mrel[(h * 16 + d) * 16 + f];
            sk = fmaf(kwp[c * 128 + h * 16 + d], ar, sk);
            sv = fmaf(vwp[c * 128 + h * 16 + d], mr, sv);
        }
        int rowoff = 128 + 256 * SLOT[et];
        unsigned short* Wp = Wpack + (size_t)l * 180224 + pre[si];
        Wp[(size_t)(rowoff + hf) * 128 + c]       = f2bf(sk);
        Wp[(size_t)(rowoff + 128 + hf) * 128 + c] = f2bf(sv);
        if (c == 0) {
            float bk = 0.f, bvv = 0.f;
            #pragma unroll
            for (int d = 0; d < 16; ++d) {
                bk  = fmaf(kbp[h * 16 + d], arel[(h * 16 + d) * 16 + f], bk);
                bvv = fmaf(vbp[h * 16 + d], mrel[(h * 16 + d) * 16 + f], bvv);
            }
            float* bp = bpack + l * 1408 + preB[si];
            bp[rowoff + hf]       = bk;
            bp[rowoff + 128 + hf] = bvv;
        }
    } else if (unit < 2944) {
        int bb = unit - 1792;
        int n = tid, k = bb & 127, mi = bb >> 7;
        const float* w; unsigned short* wt; int m;
        if (mi < 3) { w = lin_w; wt = lwt; m = mi; }
        else        { w = aw;    wt = awt; m = mi - 3; }
        wt[(size_t)m * 16384 + (size_t)n * 128 + k] =
            f2bf(w[(size_t)m * 16384 + (size_t)k * 128 + n]);
    } else {
        int k = unit - 2944, n = tid;
        if (n < 64) owt[(size_t)n * 128 + k] = f2bf(ow[(size_t)k * 64 + n]);
    }
}

// computes per-tile rowptr prefix AND zeroes deg4 back for fill's cursors
__global__ __launch_bounds__(256) void scan_tile_all(
    int* __restrict__ deg4,
    int* __restrict__ r0, int* __restrict__ r1, int* __restrict__ r2, int* __restrict__ r3,
    int* __restrict__ tsum4)
{
    const int Ndv[4] = {60000, 60000, 6000, 30000};
    __shared__ int ls[256];
    int et = blockIdx.y;
    int n = Ndv[et];
    int* deg = deg4 + et * 60000;
    int* rowptr = et == 0 ? r0 : et == 1 ? r1 : et == 2 ? r2 : r3;
    int b = blockIdx.x, tid = threadIdx.x;
    int base = b * 1024 + tid * 4;
    int v0 = 0, v1 = 0, v2 = 0, v3 = 0;
    if (base + 3 < n) {
        int4 t = *(const int4*)(deg + base);
        v0 = t.x; v1 = t.y; v2 = t.z; v3 = t.w;
        *(int4*)(deg + base) = make_int4(0, 0, 0, 0);
    } else {
        if (base + 0 < n) { v0 = deg[base + 0]; deg[base + 0] = 0; }
        if (base + 1 < n) { v1 = deg[base + 1]; deg[base + 1] = 0; }
        if (base + 2 < n) { v2 = deg[base + 2]; deg[base + 2] = 0; }
        if (base + 3 < n) { v3 = deg[base + 3]; deg[base + 3] = 0; }
    }
    int s = v0 + v1 + v2 + v3;
    ls[tid] = s;
    __syncthreads();
    #pragma unroll
    for (int off = 1; off < 256; off <<= 1) {
        int t = (tid >= off) ? ls[tid - off] : 0;
        __syncthreads();
        ls[tid] += t;
        __syncthreads();
    }
    int run = ls[tid] - s;
    int o0 = run; run += v0;
    int o1 = run; run += v1;
    int o2 = run; run += v2;
    int o3 = run;
    if (base + 3 < n) {
        *(int4*)(rowptr + base) = make_int4(o0, o1, o2, o3);
    } else {
        if (base + 0 < n) rowptr[base + 0] = o0;
        if (base + 1 < n) rowptr[base + 1] = o1;
        if (base + 2 < n) rowptr[base + 2] = o2;
    }
    if (tid == 255) tsum4[et * 64 + b] = ls[255];
}

// adds tile-prefix (computed from raw per-tile sums in LDS) + writes total
__global__ __launch_bounds__(256) void scan_add_all(
    int* __restrict__ r0, int* __restrict__ r1, int* __restrict__ r2, int* __restrict__ r3,
    const int* __restrict__ tsum4)
{
    const int Ndv[4] = {60000, 60000, 6000, 30000};
    __shared__ int ts[64];
    int et = blockIdx.y;
    int n = Ndv[et];
    int* rowptr = et == 0 ? r0 : et == 1 ? r1 : et == 2 ? r2 : r3;
    int tid = threadIdx.x;
    if (tid < 64) ts[tid] = tsum4[et * 64 + tid];
    __syncthreads();
    int i = blockIdx.x * 256 + tid;
    int tile = i >> 10;
    int pre = 0;
    for (int j = 0; j < tile; ++j) pre += ts[j];
    if (i < n) rowptr[i] += pre;
    if (blockIdx.x == 0 && tid == 0) {
        int nt = (n + 1023) >> 10, tot = 0;
        for (int j = 0; j < nt; ++j) tot += ts[j];
        rowptr[n] = tot;
    }
}

// ------------- merged: CSR fill (4 ets) + input-linear GEMM ----------------
// blocks [0,4688): fill (et = b/1172); [4688,5065): gemm_node<AF32> body
// (377 units: poi [0,118) / road [118,353) / region [353,377)).
__global__ __launch_bounds__(256, 2) void fill_nodein(
    const int* __restrict__ s0, const int* __restrict__ d0,
    const int* __restrict__ s1, const int* __restrict__ d1,
    const int* __restrict__ s2, const int* __restrict__ d2,
    const int* __restrict__ s3, const int* __restrict__ d3,
    const int* __restrict__ r0, const int* __restrict__ r1,
    const int* __restrict__ r2, const int* __restrict__ r3,
    int* __restrict__ deg4,
    int* __restrict__ c0, int* __restrict__ c1, int* __restrict__ c2, int* __restrict__ c3,
    const float* __restrict__ x0, const float* __restrict__ x1,
    const float* __restrict__ x2,
    const unsigned short* __restrict__ lwt, const float* __restrict__ lin_b,
    unsigned short* __restrict__ xs_bf)
{
    int b = blockIdx.x;
    if (b < 4688) {
        const int Ev[4] = {200000, 300000, 200000, 100000};
        int et = b / 1172, bx = b - et * 1172;
        int e = bx * 256 + threadIdx.x;
        if (e >= Ev[et]) return;
        const int* src = et == 0 ? s0 : et == 1 ? s1 : et == 2 ? s2 : s3;
        const int* dst = et == 0 ? d0 : et == 1 ? d1 : et == 2 ? d2 : d3;
        const int* rowptr = et == 0 ? r0 : et == 1 ? r1 : et == 2 ? r2 : r3;
        int* csr = et == 0 ? c0 : et == 1 ? c1 : et == 2 ? c2 : c3;
        int dd = dst[e];
        int pos = atomicAdd(&deg4[et * 60000 + dd], 1);
        csr[rowptr[dd] + pos] = src[e];
        return;
    }
    // ---- input linear + relu (AF32, no skip), 4 panels/unit ----
    const int TN[3]   = {30000, 60000, 6000};
    const int NPAN[3] = {469, 938, 94};
    const int TOFF[3] = {0, 30000, 90000};
    int nb = b - 4688, t, rb;
    if (nb < 118)      { t = 0; rb = nb; }
    else if (nb < 353) { t = 1; rb = nb - 118; }
    else               { t = 2; rb = nb - 353; }
    int p0 = rb * 4, p1 = p0 + 4;
    if (p1 > NPAN[t]) p1 = NPAN[t];
    int Nrows = TN[t];
    const float* av = (t == 0) ? x0 : (t == 1) ? x1 : x2;
    unsigned short* out = xs_bf + (size_t)TOFF[t] * 128;

    const int wave = threadIdx.x >> 6, lane = threadIdx.x & 63;
    const int quad = lane >> 4, l16 = lane & 15;

    short8 B[8][4];
    {
        const unsigned short* wb = lwt + (size_t)t * 16384 + (size_t)l16 * 128 + quad * 8;
        #pragma unroll
        for (int c = 0; c < 8; ++c)
            #pragma unroll
            for (int kc = 0; kc < 4; ++kc)
                B[c][kc] = *(const short8*)(wb + (size_t)c * 2048 + kc * 32);
    }
    short8 Acur[4];
    {
        int m = p0 * 64 + wave * 16 + l16; if (m >= Nrows) m = Nrows - 1;
        size_t base = (size_t)m * 128 + quad * 8;
        #pragma unroll
        for (int kc = 0; kc < 4; ++kc) {
            const float* ap = av + base;
            float4 f0 = *(const float4*)(ap + kc * 32);
            float4 f1 = *(const float4*)(ap + kc * 32 + 4);
            float af[8] = {f0.x, f0.y, f0.z, f0.w, f1.x, f1.y, f1.z, f1.w};
            short8 a;
            #pragma unroll
            for (int i = 0; i < 8; ++i) a[i] = (short)f2bf(af[i]);
            Acur[kc] = a;
        }
    }
    for (int p = p0; p < p1; ++p) {
        float4 Fnx[4][2];
        {
            int m = (p + 1) * 64 + wave * 16 + l16; if (m >= Nrows) m = Nrows - 1;
            size_t base = (size_t)m * 128 + quad * 8;
            #pragma unroll
            for (int kc = 0; kc < 4; ++kc) {
                const float* ap = av + base;
                Fnx[kc][0] = *(const float4*)(ap + kc * 32);
                Fnx[kc][1] = *(const float4*)(ap + kc * 32 + 4);
            }
        }
        floatx4 acc[8];
        #pragma unroll
        for (int c = 0; c < 8; ++c) acc[c] = (floatx4){0.f, 0.f, 0.f, 0.f};
        #pragma unroll
        for (int kc = 0; kc < 4; ++kc)
            #pragma unroll
            for (int c = 0; c < 8; ++c)
                acc[c] = __builtin_amdgcn_mfma_f32_16x16x32_bf16(B[c][kc], Acur[kc], acc[c], 0, 0, 0);
        int node = p * 64 + wave * 16 + l16;
        if (node < Nrows) {
            #pragma unroll
            for (int c = 0; c < 8; ++c) {
                int col0 = c * 16 + quad * 4;
                float4 bv = *(const float4*)(lin_b + t * 128 + col0);
                float o0 = fmaxf(acc[c][0] + bv.x, 0.f);
                float o1 = fmaxf(acc[c][1] + bv.y, 0.f);
                float o2 = fmaxf(acc[c][2] + bv.z, 0.f);
                float o3 = fmaxf(acc[c][3] + bv.w, 0.f);
                uint2 u;
                u.x = (unsigned)f2bf(o0) | ((unsigned)f2bf(o1) << 16);
                u.y = (unsigned)f2bf(o2) | ((unsigned)f2bf(o3) << 16);
                *(uint2*)(out + (size_t)node * 128 + col0) = u;
            }
        }
        #pragma unroll
        for (int kc = 0; kc < 4; ++kc) {
            float af[8] = {Fnx[kc][0].x, Fnx[kc][0].y, Fnx[kc][0].z, Fnx[kc][0].w,
                           Fnx[kc][1].x, Fnx[kc][1].y, Fnx[kc][1].z, Fnx[kc][1].w};
            short8 a;
            #pragma unroll
            for (int i = 0; i < 8; ++i) a[i] = (short)f2bf(af[i]);
            Acur[kc] = a;
        }
    }
}

// --------------- merged gather-side attention (all 4 edge types) ------------
// Depth-2 paired pipeline; defer-max (THR=8, exact).
__device__ __forceinline__ void attn_edge(
    uint4 k0, uint4 k1, uint4 v0, uint4 v1,
    const float* qf, float ph, float& m, float& l, float* o)
{
    float kf[16];
    up8(k0, kf); up8(k1, kf + 8);
    float a = 0.f;
    #pragma unroll
    for (int i = 0; i < 16; ++i) a = fmaf(qf[i], kf[i], a);
    a *= ph;
    float d = a - m;
    if (d > 8.f) {
        float sc = __expf(-d);
        l *= sc;
        #pragma unroll
        for (int i = 0; i < 16; ++i) o[i] *= sc;
        m = a; d = 0.f;
    }
    float w = __expf(d);
    l += w;
    float vf[16];
    up8(v0, vf); up8(v1, vf + 8);
    #pragma unroll
    for (int i = 0; i < 16; ++i) o[i] = fmaf(w, vf[i], o[i]);
}

__device__ __forceinline__ void attn_run(
    const int* __restrict__ csr, int beg, int end,
    const unsigned short* __restrict__ kbase, int ld,
    const float* qf, float ph, float& m, float& l, float* o)
{
    int n = end - beg;
    if (n <= 0) return;
    const uint4* pA = (const uint4*)(kbase + (size_t)csr[beg] * ld);
    uint4 A0 = pA[0], A1 = pA[1], A2 = pA[16], A3 = pA[17];
    uint4 B0 = A0, B1 = A1, B2 = A2, B3 = A3;
    if (n > 1) {
        const uint4* pB = (const uint4*)(kbase + (size_t)csr[beg + 1] * ld);
        B0 = pB[0]; B1 = pB[1]; B2 = pB[16]; B3 = pB[17];
    }
    int j = beg;
    for (; j + 3 < end; j += 2) {
        const uint4* pC = (const uint4*)(kbase + (size_t)csr[j + 2] * ld);
        const uint4* pD = (const uint4*)(kbase + (size_t)csr[j + 3] * ld);
        uint4 C0 = pC[0], C1 = pC[1], C2 = pC[16], C3 = pC[17];
        uint4 D0 = pD[0], D1 = pD[1], D2 = pD[16], D3 = pD[17];
        float kf0[16], kf1[16];
        up8(A0, kf0); up8(A1, kf0 + 8);
        up8(B0, kf1); up8(B1, kf1 + 8);
        float a0 = 0.f, a1 = 0.f;
        #pragma unroll
        for (int i = 0; i < 16; ++i) {
            a0 = fmaf(qf[i], kf0[i], a0);
            a1 = fmaf(qf[i], kf1[i], a1);
        }
        a0 *= ph; a1 *= ph;
        float hi = fmaxf(a0, a1);
        float d = hi - m;
        if (d > 8.f) {
            float sc = __expf(-d);
            l *= sc;
            #pragma unroll
            for (int i = 0; i < 16; ++i) o[i] *= sc;
            m = hi;
        }
        float w0 = __expf(a0 - m), w1 = __expf(a1 - m);
        l += w0 + w1;
        float vf0[16], vf1[16];
        up8(A2, vf0); up8(A3, vf0 + 8);
        up8(B2, vf1); up8(B3, vf1 + 8);
        #pragma unroll
        for (int i = 0; i < 16; ++i)
            o[i] = fmaf(w1, vf1[i], fmaf(w0, vf0[i], o[i]));
        A0 = C0; A1 = C1; A2 = C2; A3 = C3;
        B0 = D0; B1 = D1; B2 = D2; B3 = D3;
    }
    int rem = end - j;                      // 1..3
    attn_edge(A0, A1, A2, A3, qf, ph, m, l, o);
    if (rem >= 2) attn_edge(B0, B1, B2, B3, qf, ph, m, l, o);
    if (rem == 3) {
        const uint4* pC = (const uint4*)(kbase + (size_t)csr[j + 2] * ld);
        attn_edge(pC[0], pC[1], pC[16], pC[17], qf, ph, m, l, o);
    }
}

// merge partial online-softmax state across lanes (xor st)
__device__ __forceinline__ void merge_sm(float& m, float& l, float* o, int st)
{
    float mp = __shfl_xor(m, st);
    float lp = __shfl_xor(l, st);
    float mn = fmaxf(m, mp);
    float sc  = (l  > 0.f) ? __expf(m  - mn) : 0.f;
    float scp = (lp > 0.f) ? __expf(mp - mn) : 0.f;
    l = l * sc + lp * scp;
    #pragma unroll
    for (int i = 0; i < 16; ++i) {
        float op = __shfl_xor(o[i], st);
        o[i] = o[i] * sc + op * scp;
    }
    m = mn;
}

// grid: [0,3750) road (et0 & et1 on parallel lanes, 16 lanes/node) /
//       [3750,4500) region (et2, 4-way split) / [4500,5438) poi (et3 serial)
__global__ __launch_bounds__(256) void agg_all(
    const int* __restrict__ rp0, const int* __restrict__ cs0,
    const int* __restrict__ rp1, const int* __restrict__ cs1,
    const int* __restrict__ rp2, const int* __restrict__ cs2,
    const int* __restrict__ rp3, const int* __restrict__ cs3,
    const unsigned short* __restrict__ P0, const unsigned short* __restrict__ P1,
    const unsigned short* __restrict__ P2,
    const float* __restrict__ prl,      // p_rel + l*32
    unsigned short* __restrict__ num)
{
    int gb = blockIdx.x, tid = threadIdx.x;
    float qf[16], o[16], r[16];
    if (gb < 3750) {
        // ---- road: lane = (node, h, half); half0 runs et0, half1 runs et1,
        //      FULL runs in parallel; combine normalized partials via xor-8.
        int t = gb * 256 + tid;            // < 960000 exactly
        int node = t >> 4, h = t & 7, half = (t >> 3) & 1;
        const uint4* qp = (const uint4*)(P1 + (size_t)node * 640 + h * 16);
        up8(qp[0], qf); up8(qp[1], qf + 8);
        const int* csr = half ? cs1 : cs0;
        const int* rp  = half ? rp1 : rp0;
        const unsigned short* kb = half ? (P1 + 128 + h * 16) : (P0 + 128 + h * 16);
        int ld = half ? 640 : 384;
        float ph = prl[(half ? 8 : 0) + h] * 0.25f;
        float m = -INFINITY, l = 0.f;
        #pragma unroll
        for (int i = 0; i < 16; ++i) o[i] = 0.f;
        attn_run(csr, rp[node], rp[node + 1], kb, ld, qf, ph, m, l, o);
        float inv = 1.f / (l + 1e-16f);
        #pragma unroll
        for (int i = 0; i < 16; ++i) r[i] = inv * o[i];
        #pragma unroll
        for (int i = 0; i < 16; ++i) r[i] += __shfl_xor(r[i], 8);
        if (half) return;
        uint4* np = (uint4*)(num + (size_t)(30000 + node) * 128 + h * 16);
        np[0] = pk8(r); np[1] = pk8(r + 8);
    } else if (gb < 4500) {
        // ---- region: et2 (road src), 4-way edge split + shuffle merge ----
        int t = (gb - 3750) * 256 + tid;   // < 192000 exactly
        int node = t >> 5, h = t & 7, sub = (t >> 3) & 3;
        int beg0 = rp2[node], end0 = rp2[node + 1];
        int n = end0 - beg0;
        int beg = beg0 + ((n * sub) >> 2);
        int end = beg0 + ((n * (sub + 1)) >> 2);
        const uint4* qp = (const uint4*)(P2 + (size_t)node * 384 + h * 16);
        up8(qp[0], qf); up8(qp[1], qf + 8);
        float m = -INFINITY, l = 0.f;
        #pragma unroll
        for (int i = 0; i < 16; ++i) o[i] = 0.f;
        attn_run(cs2, beg, end, P1 + 384 + h * 16, 640,
                 qf, prl[16 + h] * 0.25f, m, l, o);
        merge_sm(m, l, o, 8);
        merge_sm(m, l, o, 16);
        if (sub) return;
        float inv = 1.f / (l + 1e-16f);
        #pragma unroll
        for (int i = 0; i < 16; ++i) r[i] = inv * o[i];
        uint4* np = (uint4*)(num + (size_t)(90000 + node) * 128 + h * 16);
        np[0] = pk8(r); np[1] = pk8(r + 8);
    } else {
        // ---- poi: et3 (region src), serial run ----
        int t = (gb - 4500) * 256 + tid;
        if (t >= 240000) return;
        int node = t >> 3, h = t & 7;
        const uint4* qp = (const uint4*)(P0 + (size_t)node * 384 + h * 16);
        up8(qp[0], qf); up8(qp[1], qf + 8);
        float m = -INFINITY, l = 0.f;
        #pragma unroll
        for (int i = 0; i < 16; ++i) o[i] = 0.f;
        attn_run(cs3, rp3[node], rp3[node + 1], P2 + 128 + h * 16, 384,
                 qf, prl[24 + h] * 0.25f, m, l, o);
        float inv = 1.f / (l + 1e-16f);
        #pragma unroll
        for (int i = 0; i < 16; ++i) r[i] = inv * o[i];
        uint4* np = (uint4*)(num + (size_t)node * 128 + h * 16);
        np[0] = pk8(r); np[1] = pk8(r + 8);
    }
}

extern "C" void kernel_launch(void* const* d_in, const int* in_sizes, int n_in,
                              void* d_out, int out_size, void* d_ws, size_t ws_size,
                              hipStream_t stream)
{
    (void)in_sizes; (void)n_in; (void)out_size; (void)ws_size;

    const float* xin[3] = {(const float*)d_in[0], (const float*)d_in[1], (const float*)d_in[2]};
    const int* esrc[4] = {(const int*)d_in[3], (const int*)d_in[5], (const int*)d_in[7], (const int*)d_in[9]};
    const int* edst[4] = {(const int*)d_in[4], (const int*)d_in[6], (const int*)d_in[8], (const int*)d_in[10]};
    const float* lin_w = (const float*)d_in[11];
    const float* lin_b = (const float*)d_in[12];
    const float* kw = (const float*)d_in[13];
    const float* qw = (const float*)d_in[14];
    const float* vw = (const float*)d_in[15];
    const float* aw = (const float*)d_in[16];
    const float* kb = (const float*)d_in[17];
    const float* qb = (const float*)d_in[18];
    const float* vb = (const float*)d_in[19];
    const float* ab = (const float*)d_in[20];
    const float* a_rel = (const float*)d_in[21];
    const float* m_rel = (const float*)d_in[22];
    const float* p_rel = (const float*)d_in[23];
    const float* skip  = (const float*)d_in[24];
    const float* out_w = (const float*)d_in[25];
    const float* out_b = (const float*)d_in[26];

    // workspace (float-index units; ~39.9M floats = 160 MB)
    float* ws = (float*)d_ws;
    unsigned short* num   = (unsigned short*)ws;                // 12,288,000 h
    unsigned short* xs_bf = (unsigned short*)(ws + 6144000);    // 12,288,000 h
    unsigned short* proj  = (unsigned short*)(ws + 12288000);   // 52,224,000 h
    unsigned short* Wpack = (unsigned short*)(ws + 38400000);   // 360,448 h
    unsigned short* lwt   = (unsigned short*)(ws + 38580224);   // 49,152 h
    unsigned short* awt   = (unsigned short*)(ws + 38604800);   // 98,304 h
    unsigned short* owt   = (unsigned short*)(ws + 38653952);   // 8,192 h
    float*          bpack = ws + 38658048;                      // 2,816 f
    int*            deg4  = (int*)(ws + 38660864);              // 240,000
    int*            tsum4 = (int*)(ws + 38900864);              // 256
    int* rp[4];
    rp[0] = (int*)(ws + 38901120);                              // 60,008
    rp[1] = (int*)(ws + 38961128);
    rp[2] = (int*)(ws + 39021136);                              // 6,008
    rp[3] = (int*)(ws + 39027144);                              // 30,008
    int* cs[4];
    cs[0] = (int*)(ws + 39057152);                              // 200,000
    cs[1] = (int*)(ws + 39257152);                              // 300,000
    cs[2] = (int*)(ws + 39557152);                              // 200,000
    cs[3] = (int*)(ws + 39757152);                              // 100,000

    unsigned short* P[3];
    P[0] = proj;
    P[1] = proj + (size_t)30000 * 384;
    P[2] = proj + (size_t)30000 * 384 + (size_t)60000 * 640;

    dim3 blk(256);

    // ---- CSR hist + weight prep (merged, independent) ----
    hipMemsetAsync(deg4, 0, 960000, stream);
    hist_prep<<<dim3(6224), blk, 0, stream>>>(
        edst[0], edst[1], edst[2], edst[3], deg4,
        qw, qb, kw, kb, vw, vb, a_rel, m_rel, lin_w, aw, out_w,
        Wpack, bpack, lwt, awt, owt);
    scan_tile_all<<<dim3(59, 4), blk, 0, stream>>>(deg4, rp[0], rp[1], rp[2], rp[3], tsum4);
    scan_add_all<<<dim3(235, 4), blk, 0, stream>>>(rp[0], rp[1], rp[2], rp[3], tsum4);

    // ---- CSR fill + input-linear GEMM (merged, independent) ----
    fill_nodein<<<dim3(5065), blk, 0, stream>>>(
        esrc[0], edst[0], esrc[1], edst[1], esrc[2], edst[2], esrc[3], edst[3],
        rp[0], rp[1], rp[2], rp[3], deg4, cs[0], cs[1], cs[2], cs[3],
        xin[0], xin[1], xin[2], lwt, lin_b, xs_bf);

    for (int l = 0; l < 2; ++l) {
        // packed projection per node type: [q | ka|mv ...], one fused launch
        gemm_proj_all<<<dim3(803), blk, 0, stream>>>(
            xs_bf, Wpack + (size_t)l * 180224, bpack + l * 1408, proj);

        // merged aggregation: all 4 edge types in one launch
        agg_all<<<dim3(5438), blk, 0, stream>>>(
            rp[0], cs[0], rp[1], cs[1], rp[2], cs[2], rp[3], cs[3],
            P[0], P[1], P[2], p_rel + (size_t)l * 32, num);

        // node update (fused across types)
        gemm_node<false, true, true><<<dim3(377), blk, 0, stream>>>(
            num, num + (size_t)30000 * 128, num + (size_t)90000 * 128,
            awt + (size_t)l * 3 * 16384, ab + (size_t)l * 3 * 128,
            xs_bf, skip + l * 3, xs_bf);
    }

    // ---- output projection: single GEMM over all 96000 rows ----
    gemm_out<<<dim3(375), blk, 0, stream>>>(
        xs_bf, owt, out_b, (float*)d_out, 96000);
}